// Round 2
// baseline (2927.208 us; speedup 1.0000x reference)
//
#include <hip/hip_runtime.h>
#include <cstdint>
#include <cstddef>

#define NU 30000
#define NI 20000
#define NMASK 2000

static inline int cdiv(int a, int b){ return (a + b - 1) / b; }

// ===================== threefry-2x32 (exact JAX semantics) =====================
__device__ __forceinline__ uint32_t rotl32(uint32_t x, int r){ return (x<<r)|(x>>(32-r)); }

__device__ __forceinline__ void tf2x32(uint32_t k0, uint32_t k1,
                                       uint32_t x0, uint32_t x1,
                                       uint32_t& o0, uint32_t& o1)
{
  uint32_t k2 = k0 ^ k1 ^ 0x1BD11BDAu;
  x0 += k0; x1 += k1;
#define TFR(r) { x0 += x1; x1 = rotl32(x1,(r)); x1 ^= x0; }
  TFR(13) TFR(15) TFR(26) TFR(6)
  x0 += k1; x1 += k2 + 1u;
  TFR(17) TFR(29) TFR(16) TFR(24)
  x0 += k2; x1 += k0 + 2u;
  TFR(13) TFR(15) TFR(26) TFR(6)
  x0 += k0; x1 += k1 + 3u;
  TFR(17) TFR(29) TFR(16) TFR(24)
  x0 += k1; x1 += k2 + 4u;
  TFR(13) TFR(15) TFR(26) TFR(6)
  x0 += k2; x1 += k0 + 5u;
#undef TFR
  o0 = x0; o1 = x1;
}

// jax_threefry_partitionable=True (default since JAX 0.4.30) semantics:
// split(key) -> _threefry_split_foldlike: counts = iota_2x32_shape((2,)):
//   hi=[0,0], lo=[0,1]; new_key = tf(key, 0,0) pair; subkey = tf(key, 0,1) pair.
// _shuffle does 2 rounds of {key,subkey = split(key); bits = random_bits(subkey)}.
__global__ void seed_kernel(uint32_t* __restrict__ sk)
{
  if (threadIdx.x == 0 && blockIdx.x == 0) {
    uint32_t c0,c1, s0,s1, t0,t1;
    tf2x32(0u,42u, 0u,0u, c0,c1);   // carry key after round-1 split
    tf2x32(0u,42u, 0u,1u, s0,s1);   // subkey round 1
    tf2x32(c0,c1, 0u,1u, t0,t1);    // subkey round 2
    sk[0]=s0; sk[1]=s1;
    sk[2]=t0; sk[3]=t1;
  }
}

// partitionable random_bits(subkey, 32, (n,)): for flat index i,
// (b1,b2) = tf(subkey, hi32(i)=0, lo32(i)=i); bits[i] = b1 ^ b2.
__global__ __launch_bounds__(256) void bits_kernel(const uint32_t* __restrict__ sk, int which,
                                                   uint32_t* __restrict__ bits, int n)
{
  int i = blockIdx.x*256 + threadIdx.x;
  if (i < n) {
    uint32_t o0,o1;
    tf2x32(sk[2*which], sk[2*which+1], 0u, (uint32_t)i, o0,o1);
    bits[i] = o0 ^ o1;
  }
}

// stable ascending sort by u32 key via O(n^2) rank; reproduces lax.sort_key_val exactly
#define SORT_CHUNK 10000
__global__ __launch_bounds__(256) void rank_sort_kernel(
    const uint32_t* __restrict__ keys, const uint32_t* __restrict__ vin,
    uint32_t* __restrict__ vout, int n, int ident)
{
  __shared__ uint32_t lk[SORT_CHUNK];
  int i = blockIdx.x*256 + threadIdx.x;
  uint32_t k = (i < n) ? keys[i] : 0u;
  int rank = 0;
  for (int c0 = 0; c0 < n; c0 += SORT_CHUNK) {
    int csz = min(SORT_CHUNK, n - c0);
    __syncthreads();
    for (int j = threadIdx.x; j < csz; j += 256) lk[j] = keys[c0 + j];
    __syncthreads();
    if (i < n) {
      const uint4* lk4 = reinterpret_cast<const uint4*>(lk);
      for (int j = 0; j < csz; j += 4) {   // csz divisible by 4 here
        uint4 kv = lk4[j >> 2];
        int g = c0 + j;
        rank += (int)(kv.x < k) | (int)((kv.x == k) & (g     < i));
        rank += (int)(kv.y < k) | (int)((kv.y == k) & (g + 1 < i));
        rank += (int)(kv.z < k) | (int)((kv.z == k) & (g + 2 < i));
        rank += (int)(kv.w < k) | (int)((kv.w == k) & (g + 3 < i));
      }
    }
  }
  if (i < n) vout[rank] = ident ? (uint32_t)i : vin[i];
}

__global__ __launch_bounds__(256) void mask_kernel(const uint32_t* __restrict__ perm,
                                                   float* __restrict__ mask_out,
                                                   int* __restrict__ flag)
{
  int i = blockIdx.x*256 + threadIdx.x;
  if (i < NMASK) {
    uint32_t v = perm[i];
    mask_out[i] = (float)v;
    flag[v] = 1;
  }
}

// ===================== GEMM: out(N,64) = X(N,K) @ W(64,K)^T + b =====================
// 64x64 tile, K-chunk 32, LDS stored transposed [kk][r] for float4 fragment reads.
__global__ __launch_bounds__(256) void gemm64_kernel(
    const float* __restrict__ X, const float* __restrict__ W, const float* __restrict__ bias,
    float* __restrict__ out, int N, int K)
{
  __shared__ float Xs[32][68];
  __shared__ float Ws[32][68];
  const int tid = threadIdx.x;
  const int row0 = blockIdx.x * 64;
  const int tc = (tid & 15) * 4;
  const int tr = ((tid >> 4) & 15) * 4;
  float acc[4][4];
#pragma unroll
  for (int i=0;i<4;i++)
#pragma unroll
    for (int j=0;j<4;j++) acc[i][j]=0.f;

  const int lr = tid >> 3;        // 0..31
  const int lk = (tid & 7) * 4;   // 0..28

  for (int k0 = 0; k0 < K; k0 += 32) {
    {
      float4 v0 = make_float4(0.f,0.f,0.f,0.f), v1 = make_float4(0.f,0.f,0.f,0.f);
      int g0 = row0 + lr, g1 = row0 + lr + 32;
      if (g0 < N) v0 = *reinterpret_cast<const float4*>(X + (size_t)g0*K + k0 + lk);
      if (g1 < N) v1 = *reinterpret_cast<const float4*>(X + (size_t)g1*K + k0 + lk);
      Xs[lk+0][lr]=v0.x; Xs[lk+1][lr]=v0.y; Xs[lk+2][lr]=v0.z; Xs[lk+3][lr]=v0.w;
      Xs[lk+0][lr+32]=v1.x; Xs[lk+1][lr+32]=v1.y; Xs[lk+2][lr+32]=v1.z; Xs[lk+3][lr+32]=v1.w;
      float4 w0 = *reinterpret_cast<const float4*>(W + (size_t)lr*K + k0 + lk);
      float4 w1 = *reinterpret_cast<const float4*>(W + (size_t)(lr+32)*K + k0 + lk);
      Ws[lk+0][lr]=w0.x; Ws[lk+1][lr]=w0.y; Ws[lk+2][lr]=w0.z; Ws[lk+3][lr]=w0.w;
      Ws[lk+0][lr+32]=w1.x; Ws[lk+1][lr+32]=w1.y; Ws[lk+2][lr+32]=w1.z; Ws[lk+3][lr+32]=w1.w;
    }
    __syncthreads();
#pragma unroll
    for (int kk = 0; kk < 32; ++kk) {
      float4 xv = *reinterpret_cast<const float4*>(&Xs[kk][tr]);
      float4 wv = *reinterpret_cast<const float4*>(&Ws[kk][tc]);
      float xr[4] = {xv.x,xv.y,xv.z,xv.w};
      float wr[4] = {wv.x,wv.y,wv.z,wv.w};
#pragma unroll
      for (int i=0;i<4;i++)
#pragma unroll
        for (int j=0;j<4;j++)
          acc[i][j] = fmaf(xr[i], wr[j], acc[i][j]);
    }
    __syncthreads();
  }
#pragma unroll
  for (int i=0;i<4;i++) {
    int gr = row0 + tr + i;
    if (gr < N) {
      float4 o;
      o.x = acc[i][0] + bias[tc+0];
      o.y = acc[i][1] + bias[tc+1];
      o.z = acc[i][2] + bias[tc+2];
      o.w = acc[i][3] + bias[tc+3];
      *reinterpret_cast<float4*>(out + (size_t)gr*64 + tc) = o;
    }
  }
}

// column mean of (n,64) matrix into mean[64] (mean pre-zeroed)
__global__ __launch_bounds__(256) void colmean_kernel(const float* __restrict__ a,
                                                      float* __restrict__ mean,
                                                      int n, float inv_n)
{
  __shared__ float red[256];
  int lane = threadIdx.x & 63;
  int w = threadIdx.x >> 6;
  float s = 0.f;
  for (int r = blockIdx.x*4 + w; r < n; r += gridDim.x*4)
    s += a[(size_t)r*64 + lane];
  red[threadIdx.x] = s;
  __syncthreads();
  if (threadIdx.x < 64) {
    float t = red[lane] + red[64+lane] + red[128+lane] + red[192+lane];
    atomicAdd(&mean[lane], t * inv_n);
  }
}

// ===================== CSR build =====================
__global__ __launch_bounds__(256) void hist_kernel(const int* __restrict__ rows,
                                                   const int* __restrict__ cols,
                                                   int* __restrict__ cu, int* __restrict__ ci, int nnz)
{
  int k = blockIdx.x*256 + threadIdx.x;
  if (k < nnz) { atomicAdd(&cu[rows[k]], 1); atomicAdd(&ci[cols[k]], 1); }
}

__global__ __launch_bounds__(64) void exscan_kernel(const int* __restrict__ cnt,
                                                    int* __restrict__ ptr, int n)
{
  int lane = threadIdx.x;
  int carry = 0;
  for (int base = 0; base < n; base += 64) {
    int i = base + lane;
    int v = (i < n) ? cnt[i] : 0;
    int s = v;
#pragma unroll
    for (int off = 1; off < 64; off <<= 1) {
      int t = __shfl_up(s, off);
      if (lane >= off) s += t;
    }
    if (i < n) ptr[i] = carry + s - v;
    carry += __shfl(s, 63);
  }
  if (lane == 0) ptr[n] = carry;
}

__global__ __launch_bounds__(256) void scatter_kernel(
    const int* __restrict__ rows, const int* __restrict__ cols, const float* __restrict__ vals,
    int* __restrict__ cur_u, int* __restrict__ cur_i,
    int* __restrict__ idx_u, float* __restrict__ val_u,
    int* __restrict__ idx_i, float* __restrict__ val_i, int nnz)
{
  int k = blockIdx.x*256 + threadIdx.x;
  if (k < nnz) {
    int r = rows[k], c = cols[k];
    float v = vals[k];
    int pu = atomicAdd(&cur_u[r], 1);
    idx_u[pu] = c; val_u[pu] = v;
    int pi = atomicAdd(&cur_i[c], 1);
    idx_i[pi] = r; val_i[pi] = v;
  }
}

// ===================== SpMM (one wave per row, lane = embedding column) =====================
template<int SOFTMAX, int MASKSUB>
__global__ __launch_bounds__(256) void spmm_kernel(
    const int* __restrict__ ptr, const int* __restrict__ idx, const float* __restrict__ val,
    const float* __restrict__ x, const int* __restrict__ flag, const float* __restrict__ sub,
    float* __restrict__ out, int nrows)
{
  int row = blockIdx.x*4 + (threadIdx.x >> 6);
  int lane = threadIdx.x & 63;
  if (row >= nrows) return;
  int p0 = ptr[row], p1 = ptr[row+1];
  float acc = 0.f;
  float subv = 0.f;
  if (MASKSUB) subv = sub[lane];
  for (int p = p0; p < p1; ++p) {
    int j = idx[p];
    float v = val[p];
    float xv = x[(size_t)j*64 + lane];
    if (MASKSUB) { if (flag[j]) xv = subv; }
    acc = fmaf(v, xv, acc);
  }
  if (SOFTMAX) {
    float m = acc;
#pragma unroll
    for (int o=32;o;o>>=1) m = fmaxf(m, __shfl_xor(m, o));
    float e = expf(acc - m);
    float s = e;
#pragma unroll
    for (int o=32;o;o>>=1) s += __shfl_xor(s, o);
    acc = e / s;
  }
  out[(size_t)row*64 + lane] = acc;
}

// ===================== final combine: mean of 3 + weighted l2-normalized terms =====================
__global__ __launch_bounds__(256) void combine_kernel(
    const float* e0, const float* e1, const float* e2,
    const float* m1, const float* m2,
    const float* c1, const float* c2,
    float* outg, int n)
{
  int row = blockIdx.x*4 + (threadIdx.x >> 6);
  int lane = threadIdx.x & 63;
  if (row >= n) return;
  size_t i = (size_t)row*64 + lane;
  float a = e0[i], b = e1[i], c = e2[i];
  float v1 = m1[i], v2 = m2[i], v3 = c1[i], v4 = c2[i];
  float n1 = v1*v1, n2 = v2*v2, n3 = v3*v3, n4 = v4*v4;
#pragma unroll
  for (int o=32;o;o>>=1) {
    n1 += __shfl_xor(n1, o);
    n2 += __shfl_xor(n2, o);
    n3 += __shfl_xor(n3, o);
    n4 += __shfl_xor(n4, o);
  }
  n1 = fmaxf(sqrtf(n1), 1e-12f);
  n2 = fmaxf(sqrtf(n2), 1e-12f);
  n3 = fmaxf(sqrtf(n3), 1e-12f);
  n4 = fmaxf(sqrtf(n4), 1e-12f);
  outg[i] = (a+b+c)*(1.f/3.f)
          + 0.02f*(v1/n1) + 0.02f*(v2/n2)
          + 0.30f*(v3/n3) + 0.30f*(v4/n4);
}

// ===================== host =====================
extern "C" void kernel_launch(void* const* d_in, const int* in_sizes, int n_in,
                              void* d_out, int out_size, void* d_ws, size_t ws_size,
                              hipStream_t stream)
{
  const int*   ui_rows     = (const int*)d_in[0];
  const int*   ui_cols     = (const int*)d_in[1];
  const float* ui_vals     = (const float*)d_in[2];
  const float* image_feats = (const float*)d_in[3];
  const float* text_feats  = (const float*)d_in[4];
  const float* user_feats0 = (const float*)d_in[5];
  const float* item_title  = (const float*)d_in[6];
  const float* W_img = (const float*)d_in[7];
  const float* b_img = (const float*)d_in[8];
  const float* W_txt = (const float*)d_in[9];
  const float* b_txt = (const float*)d_in[10];
  const float* W_usr = (const float*)d_in[11];
  const float* b_usr = (const float*)d_in[12];
  const float* W_itm = (const float*)d_in[13];
  const float* b_itm = (const float*)d_in[14];
  const float* user_id_emb = (const float*)d_in[15];
  const float* item_id_emb = (const float*)d_in[16];
  const int nnz = in_sizes[0];

  float* out = (float*)d_out;
  const size_t OU = (size_t)NU*64, OI = (size_t)NI*64;
  size_t off = 0;
  float* o_ug   = out + off; off += OU;   // u_g
  float* o_ig   = out + off; off += OI;   // i_g
  float* o_ii   = out + off; off += OI;   // image_item
  float* o_ti   = out + off; off += OI;   // text_item
  float* o_iu   = out + off; off += OU;   // image_user
  float* o_tu   = out + off; off += OU;   // text_user
  float* o_ue   = out + off; off += OU;   // usr_e
  float* o_ifo  = out + off; off += OI;   // item_feats_out
  float* o_up   = out + off; off += OU;   // user_prof
  float* o_ip   = out + off; off += OI;   // item_prof
  float* o_ufi  = out + off; off += OU;   // user_feat_from_item
  float* o_mask = out + off; off += NMASK;// mask_nodes (as float)
  float* o_ri   = out + off; off += OI;   // raw_image
  float* o_rt   = out + off; off += OI;   // raw_text
  float* o_rit  = out + off; off += OI;   // raw_item

  // workspace layout (accumulator zone first, memset each call)
  char* wp = (char*)d_ws;
  auto walloc = [&](size_t bytes) -> char* {
    char* r = wp; wp += (bytes + 255) & ~(size_t)255; return r;
  };
  int*   cnt_u = (int*)  walloc((size_t)NU*4);
  int*   cnt_i = (int*)  walloc((size_t)NI*4);
  int*   flag  = (int*)  walloc((size_t)NI*4);
  float* means = (float*)walloc(3*64*4);
  size_t zero_bytes = (size_t)(wp - (char*)d_ws);
  uint32_t* sk    = (uint32_t*)walloc(4*4);
  uint32_t* bits  = (uint32_t*)walloc((size_t)NI*4);
  uint32_t* permA = (uint32_t*)walloc((size_t)NI*4);
  uint32_t* permB = (uint32_t*)walloc((size_t)NI*4);
  int*   ptr_u = (int*)  walloc((size_t)(NU+1)*4);
  int*   ptr_i = (int*)  walloc((size_t)(NI+1)*4);
  int*   cur_u = (int*)  walloc((size_t)NU*4);
  int*   cur_i = (int*)  walloc((size_t)NI*4);
  int*   idx_u = (int*)  walloc((size_t)nnz*4);
  float* val_u = (float*)walloc((size_t)nnz*4);
  int*   idx_i = (int*)  walloc((size_t)nnz*4);
  float* val_i = (float*)walloc((size_t)nnz*4);
  float* u1    = (float*)walloc(OU*4);
  float* i1    = (float*)walloc(OI*4);
  float* mean_img = means, *mean_txt = means + 64, *mean_itm = means + 128;

  hipMemsetAsync(d_ws, 0, zero_bytes, stream);

  // --- mask_nodes: exact JAX permutation(key(42), 20000)[:2000], partitionable path ---
  seed_kernel<<<1, 64, 0, stream>>>(sk);
  bits_kernel<<<cdiv(NI,256), 256, 0, stream>>>(sk, 0, bits, NI);
  rank_sort_kernel<<<cdiv(NI,256), 256, 0, stream>>>(bits, nullptr, permA, NI, 1);
  bits_kernel<<<cdiv(NI,256), 256, 0, stream>>>(sk, 1, bits, NI);
  rank_sort_kernel<<<cdiv(NI,256), 256, 0, stream>>>(bits, permA, permB, NI, 0);
  mask_kernel<<<cdiv(NMASK,256), 256, 0, stream>>>(permB, o_mask, flag);

  // --- raw projections (on UNMASKED inputs) ---
  gemm64_kernel<<<cdiv(NI,64), 256, 0, stream>>>(image_feats, W_img, b_img, o_ri,  NI, 4096);
  gemm64_kernel<<<cdiv(NI,64), 256, 0, stream>>>(text_feats,  W_txt, b_txt, o_rt,  NI, 768);
  gemm64_kernel<<<cdiv(NI,64), 256, 0, stream>>>(item_title,  W_itm, b_itm, o_rit, NI, 1536);
  gemm64_kernel<<<cdiv(NU,64), 256, 0, stream>>>(user_feats0, W_usr, b_usr, o_ue,  NU, 1536);

  // masked-row projection == column-mean of raw projection (projection is linear)
  colmean_kernel<<<128, 256, 0, stream>>>(o_ri,  mean_img, NI, 1.f/NI);
  colmean_kernel<<<128, 256, 0, stream>>>(o_rt,  mean_txt, NI, 1.f/NI);
  colmean_kernel<<<128, 256, 0, stream>>>(o_rit, mean_itm, NI, 1.f/NI);

  // --- CSR build (rows->users, cols->items) ---
  hist_kernel<<<cdiv(nnz,256), 256, 0, stream>>>(ui_rows, ui_cols, cnt_u, cnt_i, nnz);
  exscan_kernel<<<1, 64, 0, stream>>>(cnt_u, ptr_u, NU);
  exscan_kernel<<<1, 64, 0, stream>>>(cnt_i, ptr_i, NI);
  hipMemcpyAsync(cur_u, ptr_u, (size_t)NU*4, hipMemcpyDeviceToDevice, stream);
  hipMemcpyAsync(cur_i, ptr_i, (size_t)NI*4, hipMemcpyDeviceToDevice, stream);
  scatter_kernel<<<cdiv(nnz,256), 256, 0, stream>>>(ui_rows, ui_cols, ui_vals,
      cur_u, cur_i, idx_u, val_u, idx_i, val_i, nnz);

  const int GU = cdiv(NU,4), GI = cdiv(NI,4);
  // modality propagation (mask substitution fused into gather)
  spmm_kernel<0,1><<<GU,256,0,stream>>>(ptr_u, idx_u, val_u, o_ri,  flag, mean_img, o_iu,  NU);
  spmm_kernel<0,0><<<GI,256,0,stream>>>(ptr_i, idx_i, val_i, o_iu,  nullptr, nullptr, o_ii,  NI);
  spmm_kernel<0,1><<<GU,256,0,stream>>>(ptr_u, idx_u, val_u, o_rt,  flag, mean_txt, o_tu,  NU);
  spmm_kernel<0,0><<<GI,256,0,stream>>>(ptr_i, idx_i, val_i, o_tu,  nullptr, nullptr, o_ti,  NI);
  spmm_kernel<0,1><<<GU,256,0,stream>>>(ptr_u, idx_u, val_u, o_rit, flag, mean_itm, o_ufi, NU);
  spmm_kernel<0,0><<<GI,256,0,stream>>>(ptr_i, idx_i, val_i, o_ufi, nullptr, nullptr, o_ifo, NI);
  // profiles
  spmm_kernel<0,0><<<GI,256,0,stream>>>(ptr_i, idx_i, val_i, o_ue,  nullptr, nullptr, o_ip,  NI);
  spmm_kernel<0,0><<<GU,256,0,stream>>>(ptr_u, idx_u, val_u, o_ip,  nullptr, nullptr, o_up,  NU);
  // LightGCN layers (u2s/i2s staged in u_g/i_g slots, consumed by combine)
  spmm_kernel<0,0><<<GU,256,0,stream>>>(ptr_u, idx_u, val_u, item_id_emb, nullptr, nullptr, u1,   NU);
  spmm_kernel<0,0><<<GI,256,0,stream>>>(ptr_i, idx_i, val_i, u1,   nullptr, nullptr, i1,   NI);
  spmm_kernel<1,0><<<GU,256,0,stream>>>(ptr_u, idx_u, val_u, i1,   nullptr, nullptr, o_ug, NU);
  spmm_kernel<1,0><<<GI,256,0,stream>>>(ptr_i, idx_i, val_i, o_ug, nullptr, nullptr, o_ig, NI);

  combine_kernel<<<GU,256,0,stream>>>(user_id_emb, u1, o_ug, o_iu, o_tu, o_up, o_ufi, o_ug, NU);
  combine_kernel<<<GI,256,0,stream>>>(item_id_emb, i1, o_ig, o_ii, o_ti, o_ip, o_ifo, o_ig, NI);
}

// Round 3
// 2011.473 us; speedup vs baseline: 1.4553x; 1.4553x over previous
//
#include <hip/hip_runtime.h>
#include <cstdint>
#include <cstddef>

#define NU 30000
#define NI 20000
#define NMASK 2000

static inline int cdiv(int a, int b){ return (a + b - 1) / b; }

// ===================== threefry-2x32 (exact JAX semantics) =====================
__device__ __forceinline__ uint32_t rotl32(uint32_t x, int r){ return (x<<r)|(x>>(32-r)); }

__device__ __forceinline__ void tf2x32(uint32_t k0, uint32_t k1,
                                       uint32_t x0, uint32_t x1,
                                       uint32_t& o0, uint32_t& o1)
{
  uint32_t k2 = k0 ^ k1 ^ 0x1BD11BDAu;
  x0 += k0; x1 += k1;
#define TFR(r) { x0 += x1; x1 = rotl32(x1,(r)); x1 ^= x0; }
  TFR(13) TFR(15) TFR(26) TFR(6)
  x0 += k1; x1 += k2 + 1u;
  TFR(17) TFR(29) TFR(16) TFR(24)
  x0 += k2; x1 += k0 + 2u;
  TFR(13) TFR(15) TFR(26) TFR(6)
  x0 += k0; x1 += k1 + 3u;
  TFR(17) TFR(29) TFR(16) TFR(24)
  x0 += k1; x1 += k2 + 4u;
  TFR(13) TFR(15) TFR(26) TFR(6)
  x0 += k2; x1 += k0 + 5u;
#undef TFR
  o0 = x0; o1 = x1;
}

// jax_threefry_partitionable=True (default since JAX 0.4.30) semantics:
// split(key): new_key = tf(key,0,0) pair; subkey = tf(key,0,1) pair.
// _shuffle: 2 rounds of {key,subkey = split(key); bits = random_bits(subkey)}.
__global__ void seed_kernel(uint32_t* __restrict__ sk)
{
  if (threadIdx.x == 0 && blockIdx.x == 0) {
    uint32_t c0,c1, s0,s1, t0,t1;
    tf2x32(0u,42u, 0u,0u, c0,c1);   // carried key after round-1 split
    tf2x32(0u,42u, 0u,1u, s0,s1);   // subkey round 1
    tf2x32(c0,c1, 0u,1u, t0,t1);    // subkey round 2
    sk[0]=s0; sk[1]=s1;
    sk[2]=t0; sk[3]=t1;
  }
}

// partitionable random_bits(subkey, 32, (n,)): bits[i] = xor of tf(subkey, 0, i)
__global__ __launch_bounds__(256) void bits_kernel(const uint32_t* __restrict__ sk, int which,
                                                   uint32_t* __restrict__ bits, int n)
{
  int i = blockIdx.x*256 + threadIdx.x;
  if (i < n) {
    uint32_t o0,o1;
    tf2x32(sk[2*which], sk[2*which+1], 0u, (uint32_t)i, o0,o1);
    bits[i] = o0 ^ o1;
  }
}

// ===================== stable rank sort, j-split for parallelism =====================
// rank[i] = #{j: key[j]<key[i]} + #{j<i: key[j]==key[i]}; computed as partial sums
// over 2000-key chunks (grid.y), accumulated with atomicAdd. Exact & stable.
#define RCH 2000
__global__ __launch_bounds__(256) void rank_partial_kernel(
    const uint32_t* __restrict__ keys, int* __restrict__ rank, int n)
{
  __shared__ uint32_t lk[RCH];
  int i = blockIdx.x*256 + threadIdx.x;
  int c0 = blockIdx.y * RCH;
  int csz = min(RCH, n - c0);
  for (int j = threadIdx.x; j < csz; j += 256) lk[j] = keys[c0 + j];
  __syncthreads();
  if (i >= n) return;
  uint32_t k = keys[i];
  int r = 0;
  const uint4* lk4 = reinterpret_cast<const uint4*>(lk);
  // csz == 2000 always (20000 = 10*2000); 2000/16 = 125 exact
  for (int j = 0; j < csz; j += 16) {
    uint4 a = lk4[(j>>2)+0];
    uint4 b = lk4[(j>>2)+1];
    uint4 c = lk4[(j>>2)+2];
    uint4 d = lk4[(j>>2)+3];
    int g = c0 + j;
    r += (int)(a.x < k) | (int)((a.x == k) & (g + 0  < i));
    r += (int)(a.y < k) | (int)((a.y == k) & (g + 1  < i));
    r += (int)(a.z < k) | (int)((a.z == k) & (g + 2  < i));
    r += (int)(a.w < k) | (int)((a.w == k) & (g + 3  < i));
    r += (int)(b.x < k) | (int)((b.x == k) & (g + 4  < i));
    r += (int)(b.y < k) | (int)((b.y == k) & (g + 5  < i));
    r += (int)(b.z < k) | (int)((b.z == k) & (g + 6  < i));
    r += (int)(b.w < k) | (int)((b.w == k) & (g + 7  < i));
    r += (int)(c.x < k) | (int)((c.x == k) & (g + 8  < i));
    r += (int)(c.y < k) | (int)((c.y == k) & (g + 9  < i));
    r += (int)(c.z < k) | (int)((c.z == k) & (g + 10 < i));
    r += (int)(c.w < k) | (int)((c.w == k) & (g + 11 < i));
    r += (int)(d.x < k) | (int)((d.x == k) & (g + 12 < i));
    r += (int)(d.y < k) | (int)((d.y == k) & (g + 13 < i));
    r += (int)(d.z < k) | (int)((d.z == k) & (g + 14 < i));
    r += (int)(d.w < k) | (int)((d.w == k) & (g + 15 < i));
  }
  atomicAdd(&rank[i], r);
}

// vout[rank[i]] = ident ? i : vin[i]
__global__ __launch_bounds__(256) void scatter_rank_kernel(
    const int* __restrict__ rank, const uint32_t* __restrict__ vin,
    uint32_t* __restrict__ vout, int n, int ident)
{
  int i = blockIdx.x*256 + threadIdx.x;
  if (i < n) vout[rank[i]] = ident ? (uint32_t)i : vin[i];
}

__global__ __launch_bounds__(256) void mask_kernel(const uint32_t* __restrict__ perm,
                                                   float* __restrict__ mask_out,
                                                   int* __restrict__ flag)
{
  int i = blockIdx.x*256 + threadIdx.x;
  if (i < NMASK) {
    uint32_t v = perm[i];
    mask_out[i] = (float)v;
    flag[v] = 1;
  }
}

// ===================== GEMM: out(N,64) = X(N,K) @ W(64,K)^T + b =====================
// 64x64 tile, K-chunk 32, LDS stored transposed [kk][r] for float4 fragment reads.
__global__ __launch_bounds__(256) void gemm64_kernel(
    const float* __restrict__ X, const float* __restrict__ W, const float* __restrict__ bias,
    float* __restrict__ out, int N, int K)
{
  __shared__ float Xs[32][68];
  __shared__ float Ws[32][68];
  const int tid = threadIdx.x;
  const int row0 = blockIdx.x * 64;
  const int tc = (tid & 15) * 4;
  const int tr = ((tid >> 4) & 15) * 4;
  float acc[4][4];
#pragma unroll
  for (int i=0;i<4;i++)
#pragma unroll
    for (int j=0;j<4;j++) acc[i][j]=0.f;

  const int lr = tid >> 3;        // 0..31
  const int lk = (tid & 7) * 4;   // 0..28

  for (int k0 = 0; k0 < K; k0 += 32) {
    {
      float4 v0 = make_float4(0.f,0.f,0.f,0.f), v1 = make_float4(0.f,0.f,0.f,0.f);
      int g0 = row0 + lr, g1 = row0 + lr + 32;
      if (g0 < N) v0 = *reinterpret_cast<const float4*>(X + (size_t)g0*K + k0 + lk);
      if (g1 < N) v1 = *reinterpret_cast<const float4*>(X + (size_t)g1*K + k0 + lk);
      Xs[lk+0][lr]=v0.x; Xs[lk+1][lr]=v0.y; Xs[lk+2][lr]=v0.z; Xs[lk+3][lr]=v0.w;
      Xs[lk+0][lr+32]=v1.x; Xs[lk+1][lr+32]=v1.y; Xs[lk+2][lr+32]=v1.z; Xs[lk+3][lr+32]=v1.w;
      float4 w0 = *reinterpret_cast<const float4*>(W + (size_t)lr*K + k0 + lk);
      float4 w1 = *reinterpret_cast<const float4*>(W + (size_t)(lr+32)*K + k0 + lk);
      Ws[lk+0][lr]=w0.x; Ws[lk+1][lr]=w0.y; Ws[lk+2][lr]=w0.z; Ws[lk+3][lr]=w0.w;
      Ws[lk+0][lr+32]=w1.x; Ws[lk+1][lr+32]=w1.y; Ws[lk+2][lr+32]=w1.z; Ws[lk+3][lr+32]=w1.w;
    }
    __syncthreads();
#pragma unroll
    for (int kk = 0; kk < 32; ++kk) {
      float4 xv = *reinterpret_cast<const float4*>(&Xs[kk][tr]);
      float4 wv = *reinterpret_cast<const float4*>(&Ws[kk][tc]);
      float xr[4] = {xv.x,xv.y,xv.z,xv.w};
      float wr[4] = {wv.x,wv.y,wv.z,wv.w};
#pragma unroll
      for (int i=0;i<4;i++)
#pragma unroll
        for (int j=0;j<4;j++)
          acc[i][j] = fmaf(xr[i], wr[j], acc[i][j]);
    }
    __syncthreads();
  }
#pragma unroll
  for (int i=0;i<4;i++) {
    int gr = row0 + tr + i;
    if (gr < N) {
      float4 o;
      o.x = acc[i][0] + bias[tc+0];
      o.y = acc[i][1] + bias[tc+1];
      o.z = acc[i][2] + bias[tc+2];
      o.w = acc[i][3] + bias[tc+3];
      *reinterpret_cast<float4*>(out + (size_t)gr*64 + tc) = o;
    }
  }
}

// column mean of (n,64) matrix into mean[64] (mean pre-zeroed)
__global__ __launch_bounds__(256) void colmean_kernel(const float* __restrict__ a,
                                                      float* __restrict__ mean,
                                                      int n, float inv_n)
{
  __shared__ float red[256];
  int lane = threadIdx.x & 63;
  int w = threadIdx.x >> 6;
  float s = 0.f;
  for (int r = blockIdx.x*4 + w; r < n; r += gridDim.x*4)
    s += a[(size_t)r*64 + lane];
  red[threadIdx.x] = s;
  __syncthreads();
  if (threadIdx.x < 64) {
    float t = red[lane] + red[64+lane] + red[128+lane] + red[192+lane];
    atomicAdd(&mean[lane], t * inv_n);
  }
}

// ===================== CSR build =====================
__global__ __launch_bounds__(256) void hist_kernel(const int* __restrict__ rows,
                                                   const int* __restrict__ cols,
                                                   int* __restrict__ cu, int* __restrict__ ci, int nnz)
{
  int k = blockIdx.x*256 + threadIdx.x;
  if (k < nnz) { atomicAdd(&cu[rows[k]], 1); atomicAdd(&ci[cols[k]], 1); }
}

__global__ __launch_bounds__(64) void exscan_kernel(const int* __restrict__ cnt,
                                                    int* __restrict__ ptr, int n)
{
  int lane = threadIdx.x;
  int carry = 0;
  for (int base = 0; base < n; base += 64) {
    int i = base + lane;
    int v = (i < n) ? cnt[i] : 0;
    int s = v;
#pragma unroll
    for (int off = 1; off < 64; off <<= 1) {
      int t = __shfl_up(s, off);
      if (lane >= off) s += t;
    }
    if (i < n) ptr[i] = carry + s - v;
    carry += __shfl(s, 63);
  }
  if (lane == 0) ptr[n] = carry;
}

__global__ __launch_bounds__(256) void scatter_kernel(
    const int* __restrict__ rows, const int* __restrict__ cols, const float* __restrict__ vals,
    int* __restrict__ cur_u, int* __restrict__ cur_i,
    int* __restrict__ idx_u, float* __restrict__ val_u,
    int* __restrict__ idx_i, float* __restrict__ val_i, int nnz)
{
  int k = blockIdx.x*256 + threadIdx.x;
  if (k < nnz) {
    int r = rows[k], c = cols[k];
    float v = vals[k];
    int pu = atomicAdd(&cur_u[r], 1);
    idx_u[pu] = c; val_u[pu] = v;
    int pi = atomicAdd(&cur_i[c], 1);
    idx_i[pi] = r; val_i[pi] = v;
  }
}

// ===================== SpMM (one wave per row, lane = embedding column) =====================
template<int SOFTMAX, int MASKSUB>
__global__ __launch_bounds__(256) void spmm_kernel(
    const int* __restrict__ ptr, const int* __restrict__ idx, const float* __restrict__ val,
    const float* __restrict__ x, const int* __restrict__ flag, const float* __restrict__ sub,
    float* __restrict__ out, int nrows)
{
  int row = blockIdx.x*4 + (threadIdx.x >> 6);
  int lane = threadIdx.x & 63;
  if (row >= nrows) return;
  int p0 = ptr[row], p1 = ptr[row+1];
  float acc = 0.f;
  float subv = 0.f;
  if (MASKSUB) subv = sub[lane];
  for (int p = p0; p < p1; ++p) {
    int j = idx[p];
    float v = val[p];
    float xv = x[(size_t)j*64 + lane];
    if (MASKSUB) { if (flag[j]) xv = subv; }
    acc = fmaf(v, xv, acc);
  }
  if (SOFTMAX) {
    float m = acc;
#pragma unroll
    for (int o=32;o;o>>=1) m = fmaxf(m, __shfl_xor(m, o));
    float e = expf(acc - m);
    float s = e;
#pragma unroll
    for (int o=32;o;o>>=1) s += __shfl_xor(s, o);
    acc = e / s;
  }
  out[(size_t)row*64 + lane] = acc;
}

// ===================== final combine: mean of 3 + weighted l2-normalized terms =====================
__global__ __launch_bounds__(256) void combine_kernel(
    const float* e0, const float* e1, const float* e2,
    const float* m1, const float* m2,
    const float* c1, const float* c2,
    float* outg, int n)
{
  int row = blockIdx.x*4 + (threadIdx.x >> 6);
  int lane = threadIdx.x & 63;
  if (row >= n) return;
  size_t i = (size_t)row*64 + lane;
  float a = e0[i], b = e1[i], c = e2[i];
  float v1 = m1[i], v2 = m2[i], v3 = c1[i], v4 = c2[i];
  float n1 = v1*v1, n2 = v2*v2, n3 = v3*v3, n4 = v4*v4;
#pragma unroll
  for (int o=32;o;o>>=1) {
    n1 += __shfl_xor(n1, o);
    n2 += __shfl_xor(n2, o);
    n3 += __shfl_xor(n3, o);
    n4 += __shfl_xor(n4, o);
  }
  n1 = fmaxf(sqrtf(n1), 1e-12f);
  n2 = fmaxf(sqrtf(n2), 1e-12f);
  n3 = fmaxf(sqrtf(n3), 1e-12f);
  n4 = fmaxf(sqrtf(n4), 1e-12f);
  outg[i] = (a+b+c)*(1.f/3.f)
          + 0.02f*(v1/n1) + 0.02f*(v2/n2)
          + 0.30f*(v3/n3) + 0.30f*(v4/n4);
}

// ===================== host =====================
extern "C" void kernel_launch(void* const* d_in, const int* in_sizes, int n_in,
                              void* d_out, int out_size, void* d_ws, size_t ws_size,
                              hipStream_t stream)
{
  const int*   ui_rows     = (const int*)d_in[0];
  const int*   ui_cols     = (const int*)d_in[1];
  const float* ui_vals     = (const float*)d_in[2];
  const float* image_feats = (const float*)d_in[3];
  const float* text_feats  = (const float*)d_in[4];
  const float* user_feats0 = (const float*)d_in[5];
  const float* item_title  = (const float*)d_in[6];
  const float* W_img = (const float*)d_in[7];
  const float* b_img = (const float*)d_in[8];
  const float* W_txt = (const float*)d_in[9];
  const float* b_txt = (const float*)d_in[10];
  const float* W_usr = (const float*)d_in[11];
  const float* b_usr = (const float*)d_in[12];
  const float* W_itm = (const float*)d_in[13];
  const float* b_itm = (const float*)d_in[14];
  const float* user_id_emb = (const float*)d_in[15];
  const float* item_id_emb = (const float*)d_in[16];
  const int nnz = in_sizes[0];

  float* out = (float*)d_out;
  const size_t OU = (size_t)NU*64, OI = (size_t)NI*64;
  size_t off = 0;
  float* o_ug   = out + off; off += OU;   // u_g
  float* o_ig   = out + off; off += OI;   // i_g
  float* o_ii   = out + off; off += OI;   // image_item
  float* o_ti   = out + off; off += OI;   // text_item
  float* o_iu   = out + off; off += OU;   // image_user
  float* o_tu   = out + off; off += OU;   // text_user
  float* o_ue   = out + off; off += OU;   // usr_e
  float* o_ifo  = out + off; off += OI;   // item_feats_out
  float* o_up   = out + off; off += OU;   // user_prof
  float* o_ip   = out + off; off += OI;   // item_prof
  float* o_ufi  = out + off; off += OU;   // user_feat_from_item
  float* o_mask = out + off; off += NMASK;// mask_nodes (as float)
  float* o_ri   = out + off; off += OI;   // raw_image
  float* o_rt   = out + off; off += OI;   // raw_text
  float* o_rit  = out + off; off += OI;   // raw_item

  // workspace layout (accumulator zone first, memset each call)
  char* wp = (char*)d_ws;
  auto walloc = [&](size_t bytes) -> char* {
    char* r = wp; wp += (bytes + 255) & ~(size_t)255; return r;
  };
  int*   cnt_u = (int*)  walloc((size_t)NU*4);
  int*   cnt_i = (int*)  walloc((size_t)NI*4);
  int*   flag  = (int*)  walloc((size_t)NI*4);
  float* means = (float*)walloc(3*64*4);
  int*   rankA = (int*)  walloc((size_t)NI*4);
  int*   rankB = (int*)  walloc((size_t)NI*4);
  size_t zero_bytes = (size_t)(wp - (char*)d_ws);
  uint32_t* sk    = (uint32_t*)walloc(4*4);
  uint32_t* bits  = (uint32_t*)walloc((size_t)NI*4);
  uint32_t* permA = (uint32_t*)walloc((size_t)NI*4);
  uint32_t* permB = (uint32_t*)walloc((size_t)NI*4);
  int*   ptr_u = (int*)  walloc((size_t)(NU+1)*4);
  int*   ptr_i = (int*)  walloc((size_t)(NI+1)*4);
  int*   cur_u = (int*)  walloc((size_t)NU*4);
  int*   cur_i = (int*)  walloc((size_t)NI*4);
  int*   idx_u = (int*)  walloc((size_t)nnz*4);
  float* val_u = (float*)walloc((size_t)nnz*4);
  int*   idx_i = (int*)  walloc((size_t)nnz*4);
  float* val_i = (float*)walloc((size_t)nnz*4);
  float* u1    = (float*)walloc(OU*4);
  float* i1    = (float*)walloc(OI*4);
  float* mean_img = means, *mean_txt = means + 64, *mean_itm = means + 128;

  hipMemsetAsync(d_ws, 0, zero_bytes, stream);

  // --- mask_nodes: exact JAX permutation(key(42), 20000)[:2000], partitionable path ---
  seed_kernel<<<1, 64, 0, stream>>>(sk);
  dim3 rgrid(cdiv(NI,256), NI/RCH);
  bits_kernel<<<cdiv(NI,256), 256, 0, stream>>>(sk, 0, bits, NI);
  rank_partial_kernel<<<rgrid, 256, 0, stream>>>(bits, rankA, NI);
  scatter_rank_kernel<<<cdiv(NI,256), 256, 0, stream>>>(rankA, nullptr, permA, NI, 1);
  bits_kernel<<<cdiv(NI,256), 256, 0, stream>>>(sk, 1, bits, NI);
  rank_partial_kernel<<<rgrid, 256, 0, stream>>>(bits, rankB, NI);
  scatter_rank_kernel<<<cdiv(NI,256), 256, 0, stream>>>(rankB, permA, permB, NI, 0);
  mask_kernel<<<cdiv(NMASK,256), 256, 0, stream>>>(permB, o_mask, flag);

  // --- raw projections (on UNMASKED inputs) ---
  gemm64_kernel<<<cdiv(NI,64), 256, 0, stream>>>(image_feats, W_img, b_img, o_ri,  NI, 4096);
  gemm64_kernel<<<cdiv(NI,64), 256, 0, stream>>>(text_feats,  W_txt, b_txt, o_rt,  NI, 768);
  gemm64_kernel<<<cdiv(NI,64), 256, 0, stream>>>(item_title,  W_itm, b_itm, o_rit, NI, 1536);
  gemm64_kernel<<<cdiv(NU,64), 256, 0, stream>>>(user_feats0, W_usr, b_usr, o_ue,  NU, 1536);

  // masked-row projection == column-mean of raw projection (projection is linear)
  colmean_kernel<<<128, 256, 0, stream>>>(o_ri,  mean_img, NI, 1.f/NI);
  colmean_kernel<<<128, 256, 0, stream>>>(o_rt,  mean_txt, NI, 1.f/NI);
  colmean_kernel<<<128, 256, 0, stream>>>(o_rit, mean_itm, NI, 1.f/NI);

  // --- CSR build (rows->users, cols->items) ---
  hist_kernel<<<cdiv(nnz,256), 256, 0, stream>>>(ui_rows, ui_cols, cnt_u, cnt_i, nnz);
  exscan_kernel<<<1, 64, 0, stream>>>(cnt_u, ptr_u, NU);
  exscan_kernel<<<1, 64, 0, stream>>>(cnt_i, ptr_i, NI);
  hipMemcpyAsync(cur_u, ptr_u, (size_t)NU*4, hipMemcpyDeviceToDevice, stream);
  hipMemcpyAsync(cur_i, ptr_i, (size_t)NI*4, hipMemcpyDeviceToDevice, stream);
  scatter_kernel<<<cdiv(nnz,256), 256, 0, stream>>>(ui_rows, ui_cols, ui_vals,
      cur_u, cur_i, idx_u, val_u, idx_i, val_i, nnz);

  const int GU = cdiv(NU,4), GI = cdiv(NI,4);
  // modality propagation (mask substitution fused into gather)
  spmm_kernel<0,1><<<GU,256,0,stream>>>(ptr_u, idx_u, val_u, o_ri,  flag, mean_img, o_iu,  NU);
  spmm_kernel<0,0><<<GI,256,0,stream>>>(ptr_i, idx_i, val_i, o_iu,  nullptr, nullptr, o_ii,  NI);
  spmm_kernel<0,1><<<GU,256,0,stream>>>(ptr_u, idx_u, val_u, o_rt,  flag, mean_txt, o_tu,  NU);
  spmm_kernel<0,0><<<GI,256,0,stream>>>(ptr_i, idx_i, val_i, o_tu,  nullptr, nullptr, o_ti,  NI);
  spmm_kernel<0,1><<<GU,256,0,stream>>>(ptr_u, idx_u, val_u, o_rit, flag, mean_itm, o_ufi, NU);
  spmm_kernel<0,0><<<GI,256,0,stream>>>(ptr_i, idx_i, val_i, o_ufi, nullptr, nullptr, o_ifo, NI);
  // profiles
  spmm_kernel<0,0><<<GI,256,0,stream>>>(ptr_i, idx_i, val_i, o_ue,  nullptr, nullptr, o_ip,  NI);
  spmm_kernel<0,0><<<GU,256,0,stream>>>(ptr_u, idx_u, val_u, o_ip,  nullptr, nullptr, o_up,  NU);
  // LightGCN layers (u2s/i2s staged in u_g/i_g slots, consumed by combine)
  spmm_kernel<0,0><<<GU,256,0,stream>>>(ptr_u, idx_u, val_u, item_id_emb, nullptr, nullptr, u1,   NU);
  spmm_kernel<0,0><<<GI,256,0,stream>>>(ptr_i, idx_i, val_i, u1,   nullptr, nullptr, i1,   NI);
  spmm_kernel<1,0><<<GU,256,0,stream>>>(ptr_u, idx_u, val_u, i1,   nullptr, nullptr, o_ug, NU);
  spmm_kernel<1,0><<<GI,256,0,stream>>>(ptr_i, idx_i, val_i, o_ug, nullptr, nullptr, o_ig, NI);

  combine_kernel<<<GU,256,0,stream>>>(user_id_emb, u1, o_ug, o_iu, o_tu, o_up, o_ufi, o_ug, NU);
  combine_kernel<<<GI,256,0,stream>>>(item_id_emb, i1, o_ig, o_ii, o_ti, o_ip, o_ifo, o_ig, NI);
}

// Round 4
// 1837.914 us; speedup vs baseline: 1.5927x; 1.0944x over previous
//
#include <hip/hip_runtime.h>
#include <cstdint>
#include <cstddef>

#define NU 30000
#define NI 20000
#define NMASK 2000

static inline int cdiv(int a, int b){ return (a + b - 1) / b; }

// ===================== threefry-2x32 (exact JAX semantics) =====================
__device__ __forceinline__ uint32_t rotl32(uint32_t x, int r){ return (x<<r)|(x>>(32-r)); }

__device__ __forceinline__ void tf2x32(uint32_t k0, uint32_t k1,
                                       uint32_t x0, uint32_t x1,
                                       uint32_t& o0, uint32_t& o1)
{
  uint32_t k2 = k0 ^ k1 ^ 0x1BD11BDAu;
  x0 += k0; x1 += k1;
#define TFR(r) { x0 += x1; x1 = rotl32(x1,(r)); x1 ^= x0; }
  TFR(13) TFR(15) TFR(26) TFR(6)
  x0 += k1; x1 += k2 + 1u;
  TFR(17) TFR(29) TFR(16) TFR(24)
  x0 += k2; x1 += k0 + 2u;
  TFR(13) TFR(15) TFR(26) TFR(6)
  x0 += k0; x1 += k1 + 3u;
  TFR(17) TFR(29) TFR(16) TFR(24)
  x0 += k1; x1 += k2 + 4u;
  TFR(13) TFR(15) TFR(26) TFR(6)
  x0 += k2; x1 += k0 + 5u;
#undef TFR
  o0 = x0; o1 = x1;
}

// jax_threefry_partitionable=True (default since JAX 0.4.30) semantics:
// split(key): new_key = tf(key,0,0) pair; subkey = tf(key,0,1) pair.
// _shuffle: 2 rounds of {key,subkey = split(key); bits = random_bits(subkey)}.
__global__ void seed_kernel(uint32_t* __restrict__ sk)
{
  if (threadIdx.x == 0 && blockIdx.x == 0) {
    uint32_t c0,c1, s0,s1, t0,t1;
    tf2x32(0u,42u, 0u,0u, c0,c1);   // carried key after round-1 split
    tf2x32(0u,42u, 0u,1u, s0,s1);   // subkey round 1
    tf2x32(c0,c1, 0u,1u, t0,t1);    // subkey round 2
    sk[0]=s0; sk[1]=s1;
    sk[2]=t0; sk[3]=t1;
  }
}

// partitionable random_bits(subkey, 32, (n,)): bits[i] = xor of tf(subkey, 0, i)
__global__ __launch_bounds__(256) void bits_kernel(const uint32_t* __restrict__ sk, int which,
                                                   uint32_t* __restrict__ bits, int n)
{
  int i = blockIdx.x*256 + threadIdx.x;
  if (i < n) {
    uint32_t o0,o1;
    tf2x32(sk[2*which], sk[2*which+1], 0u, (uint32_t)i, o0,o1);
    bits[i] = o0 ^ o1;
  }
}

// ===================== stable rank sort, j-split for parallelism =====================
#define RCH 2000
__global__ __launch_bounds__(256) void rank_partial_kernel(
    const uint32_t* __restrict__ keys, int* __restrict__ rank, int n)
{
  __shared__ uint32_t lk[RCH];
  int i = blockIdx.x*256 + threadIdx.x;
  int c0 = blockIdx.y * RCH;
  int csz = min(RCH, n - c0);
  for (int j = threadIdx.x; j < csz; j += 256) lk[j] = keys[c0 + j];
  __syncthreads();
  if (i >= n) return;
  uint32_t k = keys[i];
  int r = 0;
  const uint4* lk4 = reinterpret_cast<const uint4*>(lk);
  for (int j = 0; j < csz; j += 16) {
    uint4 a = lk4[(j>>2)+0];
    uint4 b = lk4[(j>>2)+1];
    uint4 c = lk4[(j>>2)+2];
    uint4 d = lk4[(j>>2)+3];
    int g = c0 + j;
    r += (int)(a.x < k) | (int)((a.x == k) & (g + 0  < i));
    r += (int)(a.y < k) | (int)((a.y == k) & (g + 1  < i));
    r += (int)(a.z < k) | (int)((a.z == k) & (g + 2  < i));
    r += (int)(a.w < k) | (int)((a.w == k) & (g + 3  < i));
    r += (int)(b.x < k) | (int)((b.x == k) & (g + 4  < i));
    r += (int)(b.y < k) | (int)((b.y == k) & (g + 5  < i));
    r += (int)(b.z < k) | (int)((b.z == k) & (g + 6  < i));
    r += (int)(b.w < k) | (int)((b.w == k) & (g + 7  < i));
    r += (int)(c.x < k) | (int)((c.x == k) & (g + 8  < i));
    r += (int)(c.y < k) | (int)((c.y == k) & (g + 9  < i));
    r += (int)(c.z < k) | (int)((c.z == k) & (g + 10 < i));
    r += (int)(c.w < k) | (int)((c.w == k) & (g + 11 < i));
    r += (int)(d.x < k) | (int)((d.x == k) & (g + 12 < i));
    r += (int)(d.y < k) | (int)((d.y == k) & (g + 13 < i));
    r += (int)(d.z < k) | (int)((d.z == k) & (g + 14 < i));
    r += (int)(d.w < k) | (int)((d.w == k) & (g + 15 < i));
  }
  atomicAdd(&rank[i], r);
}

__global__ __launch_bounds__(256) void scatter_rank_kernel(
    const int* __restrict__ rank, const uint32_t* __restrict__ vin,
    uint32_t* __restrict__ vout, int n, int ident)
{
  int i = blockIdx.x*256 + threadIdx.x;
  if (i < n) vout[rank[i]] = ident ? (uint32_t)i : vin[i];
}

__global__ __launch_bounds__(256) void mask_kernel(const uint32_t* __restrict__ perm,
                                                   float* __restrict__ mask_out,
                                                   int* __restrict__ flag)
{
  int i = blockIdx.x*256 + threadIdx.x;
  if (i < NMASK) {
    uint32_t v = perm[i];
    mask_out[i] = (float)v;
    flag[v] = 1;
  }
}

// ===================== GEMM: out(N,64) = X(N,K) @ W(64,K)^T + b =====================
// K-split partial GEMM: grid.y = K-chunk, writes partials to pbuf (no bias).
__global__ __launch_bounds__(256) void gemm_part_kernel(
    const float* __restrict__ X, const float* __restrict__ W,
    float* __restrict__ pbuf, int N, int K, int klen)
{
  __shared__ float Xs[32][68];
  __shared__ float Ws[32][68];
  const int tid = threadIdx.x;
  const int row0 = blockIdx.x * 64;
  const int kbeg = blockIdx.y * klen;
  const int tc = (tid & 15) * 4;
  const int tr = ((tid >> 4) & 15) * 4;
  float acc[4][4];
#pragma unroll
  for (int i=0;i<4;i++)
#pragma unroll
    for (int j=0;j<4;j++) acc[i][j]=0.f;

  const int lr = tid >> 3;        // 0..31
  const int lk = (tid & 7) * 4;   // 0..28

  for (int k0 = kbeg; k0 < kbeg + klen; k0 += 32) {
    {
      float4 v0 = make_float4(0.f,0.f,0.f,0.f), v1 = make_float4(0.f,0.f,0.f,0.f);
      int g0 = row0 + lr, g1 = row0 + lr + 32;
      if (g0 < N) v0 = *reinterpret_cast<const float4*>(X + (size_t)g0*K + k0 + lk);
      if (g1 < N) v1 = *reinterpret_cast<const float4*>(X + (size_t)g1*K + k0 + lk);
      Xs[lk+0][lr]=v0.x; Xs[lk+1][lr]=v0.y; Xs[lk+2][lr]=v0.z; Xs[lk+3][lr]=v0.w;
      Xs[lk+0][lr+32]=v1.x; Xs[lk+1][lr+32]=v1.y; Xs[lk+2][lr+32]=v1.z; Xs[lk+3][lr+32]=v1.w;
      float4 w0 = *reinterpret_cast<const float4*>(W + (size_t)lr*K + k0 + lk);
      float4 w1 = *reinterpret_cast<const float4*>(W + (size_t)(lr+32)*K + k0 + lk);
      Ws[lk+0][lr]=w0.x; Ws[lk+1][lr]=w0.y; Ws[lk+2][lr]=w0.z; Ws[lk+3][lr]=w0.w;
      Ws[lk+0][lr+32]=w1.x; Ws[lk+1][lr+32]=w1.y; Ws[lk+2][lr+32]=w1.z; Ws[lk+3][lr+32]=w1.w;
    }
    __syncthreads();
#pragma unroll
    for (int kk = 0; kk < 32; ++kk) {
      float4 xv = *reinterpret_cast<const float4*>(&Xs[kk][tr]);
      float4 wv = *reinterpret_cast<const float4*>(&Ws[kk][tc]);
      float xr[4] = {xv.x,xv.y,xv.z,xv.w};
      float wr[4] = {wv.x,wv.y,wv.z,wv.w};
#pragma unroll
      for (int i=0;i<4;i++)
#pragma unroll
        for (int j=0;j<4;j++)
          acc[i][j] = fmaf(xr[i], wr[j], acc[i][j]);
    }
    __syncthreads();
  }
  float* pb = pbuf + (size_t)blockIdx.y * N * 64;
#pragma unroll
  for (int i=0;i<4;i++) {
    int gr = row0 + tr + i;
    if (gr < N)
      *reinterpret_cast<float4*>(pb + (size_t)gr*64 + tc) =
        make_float4(acc[i][0], acc[i][1], acc[i][2], acc[i][3]);
  }
}

// out[r][c] = bias[c] + sum_ch pbuf[ch][r][c]
__global__ __launch_bounds__(256) void gemm_reduce_kernel(
    const float* __restrict__ pbuf, const float* __restrict__ bias,
    float* __restrict__ out, int N, int nch)
{
  int i = blockIdx.x*256 + threadIdx.x;
  if (i >= N*64) return;
  float s = bias[i & 63];
  for (int ch = 0; ch < nch; ++ch) s += pbuf[(size_t)ch*N*64 + i];
  out[i] = s;
}

// fallback single-pass GEMM (used if workspace too small for partials)
__global__ __launch_bounds__(256) void gemm64_kernel(
    const float* __restrict__ X, const float* __restrict__ W, const float* __restrict__ bias,
    float* __restrict__ out, int N, int K)
{
  __shared__ float Xs[32][68];
  __shared__ float Ws[32][68];
  const int tid = threadIdx.x;
  const int row0 = blockIdx.x * 64;
  const int tc = (tid & 15) * 4;
  const int tr = ((tid >> 4) & 15) * 4;
  float acc[4][4];
#pragma unroll
  for (int i=0;i<4;i++)
#pragma unroll
    for (int j=0;j<4;j++) acc[i][j]=0.f;
  const int lr = tid >> 3;
  const int lk = (tid & 7) * 4;
  for (int k0 = 0; k0 < K; k0 += 32) {
    {
      float4 v0 = make_float4(0.f,0.f,0.f,0.f), v1 = make_float4(0.f,0.f,0.f,0.f);
      int g0 = row0 + lr, g1 = row0 + lr + 32;
      if (g0 < N) v0 = *reinterpret_cast<const float4*>(X + (size_t)g0*K + k0 + lk);
      if (g1 < N) v1 = *reinterpret_cast<const float4*>(X + (size_t)g1*K + k0 + lk);
      Xs[lk+0][lr]=v0.x; Xs[lk+1][lr]=v0.y; Xs[lk+2][lr]=v0.z; Xs[lk+3][lr]=v0.w;
      Xs[lk+0][lr+32]=v1.x; Xs[lk+1][lr+32]=v1.y; Xs[lk+2][lr+32]=v1.z; Xs[lk+3][lr+32]=v1.w;
      float4 w0 = *reinterpret_cast<const float4*>(W + (size_t)lr*K + k0 + lk);
      float4 w1 = *reinterpret_cast<const float4*>(W + (size_t)(lr+32)*K + k0 + lk);
      Ws[lk+0][lr]=w0.x; Ws[lk+1][lr]=w0.y; Ws[lk+2][lr]=w0.z; Ws[lk+3][lr]=w0.w;
      Ws[lk+0][lr+32]=w1.x; Ws[lk+1][lr+32]=w1.y; Ws[lk+2][lr+32]=w1.z; Ws[lk+3][lr+32]=w1.w;
    }
    __syncthreads();
#pragma unroll
    for (int kk = 0; kk < 32; ++kk) {
      float4 xv = *reinterpret_cast<const float4*>(&Xs[kk][tr]);
      float4 wv = *reinterpret_cast<const float4*>(&Ws[kk][tc]);
      float xr[4] = {xv.x,xv.y,xv.z,xv.w};
      float wr[4] = {wv.x,wv.y,wv.z,wv.w};
#pragma unroll
      for (int i=0;i<4;i++)
#pragma unroll
        for (int j=0;j<4;j++)
          acc[i][j] = fmaf(xr[i], wr[j], acc[i][j]);
    }
    __syncthreads();
  }
#pragma unroll
  for (int i=0;i<4;i++) {
    int gr = row0 + tr + i;
    if (gr < N) {
      float4 o;
      o.x = acc[i][0] + bias[tc+0];
      o.y = acc[i][1] + bias[tc+1];
      o.z = acc[i][2] + bias[tc+2];
      o.w = acc[i][3] + bias[tc+3];
      *reinterpret_cast<float4*>(out + (size_t)gr*64 + tc) = o;
    }
  }
}

// column mean of (n,64) matrix into mean[64] (mean pre-zeroed)
__global__ __launch_bounds__(256) void colmean_kernel(const float* __restrict__ a,
                                                      float* __restrict__ mean,
                                                      int n, float inv_n)
{
  __shared__ float red[256];
  int lane = threadIdx.x & 63;
  int w = threadIdx.x >> 6;
  float s = 0.f;
  for (int r = blockIdx.x*4 + w; r < n; r += gridDim.x*4)
    s += a[(size_t)r*64 + lane];
  red[threadIdx.x] = s;
  __syncthreads();
  if (threadIdx.x < 64) {
    float t = red[lane] + red[64+lane] + red[128+lane] + red[192+lane];
    atomicAdd(&mean[lane], t * inv_n);
  }
}

// ===================== CSR build =====================
__global__ __launch_bounds__(256) void hist_kernel(const int* __restrict__ rows,
                                                   const int* __restrict__ cols,
                                                   int* __restrict__ cu, int* __restrict__ ci, int nnz)
{
  int k = blockIdx.x*256 + threadIdx.x;
  if (k < nnz) { atomicAdd(&cu[rows[k]], 1); atomicAdd(&ci[cols[k]], 1); }
}

__global__ __launch_bounds__(64) void exscan_kernel(const int* __restrict__ cnt,
                                                    int* __restrict__ ptr, int n)
{
  int lane = threadIdx.x;
  int carry = 0;
  for (int base = 0; base < n; base += 64) {
    int i = base + lane;
    int v = (i < n) ? cnt[i] : 0;
    int s = v;
#pragma unroll
    for (int off = 1; off < 64; off <<= 1) {
      int t = __shfl_up(s, off);
      if (lane >= off) s += t;
    }
    if (i < n) ptr[i] = carry + s - v;
    carry += __shfl(s, 63);
  }
  if (lane == 0) ptr[n] = carry;
}

__global__ __launch_bounds__(256) void scatter_kernel(
    const int* __restrict__ rows, const int* __restrict__ cols, const float* __restrict__ vals,
    int* __restrict__ cur_u, int* __restrict__ cur_i,
    int* __restrict__ idx_u, float* __restrict__ val_u,
    int* __restrict__ idx_i, float* __restrict__ val_i, int nnz)
{
  int k = blockIdx.x*256 + threadIdx.x;
  if (k < nnz) {
    int r = rows[k], c = cols[k];
    float v = vals[k];
    int pu = atomicAdd(&cur_u[r], 1);
    idx_u[pu] = c; val_u[pu] = v;
    int pi = atomicAdd(&cur_i[c], 1);
    idx_i[pi] = r; val_i[pi] = v;
  }
}

// ===================== SpMM (one wave per row, lane = embedding column) =====================
template<int SOFTMAX, int MASKSUB>
__global__ __launch_bounds__(256) void spmm_kernel(
    const int* __restrict__ ptr, const int* __restrict__ idx, const float* __restrict__ val,
    const float* __restrict__ x, const int* __restrict__ flag, const float* __restrict__ sub,
    float* __restrict__ out, int nrows)
{
  int row = blockIdx.x*4 + (threadIdx.x >> 6);
  int lane = threadIdx.x & 63;
  if (row >= nrows) return;
  int p0 = ptr[row], p1 = ptr[row+1];
  float acc = 0.f;
  float subv = 0.f;
  if (MASKSUB) subv = sub[lane];
  for (int p = p0; p < p1; ++p) {
    int j = idx[p];
    float v = val[p];
    float xv = x[(size_t)j*64 + lane];
    if (MASKSUB) { if (flag[j]) xv = subv; }
    acc = fmaf(v, xv, acc);
  }
  if (SOFTMAX) {
    float m = acc;
#pragma unroll
    for (int o=32;o;o>>=1) m = fmaxf(m, __shfl_xor(m, o));
    float e = expf(acc - m);
    float s = e;
#pragma unroll
    for (int o=32;o;o>>=1) s += __shfl_xor(s, o);
    acc = e / s;
  }
  out[(size_t)row*64 + lane] = acc;
}

// ===================== final combine =====================
__global__ __launch_bounds__(256) void combine_kernel(
    const float* e0, const float* e1, const float* e2,
    const float* m1, const float* m2,
    const float* c1, const float* c2,
    float* outg, int n)
{
  int row = blockIdx.x*4 + (threadIdx.x >> 6);
  int lane = threadIdx.x & 63;
  if (row >= n) return;
  size_t i = (size_t)row*64 + lane;
  float a = e0[i], b = e1[i], c = e2[i];
  float v1 = m1[i], v2 = m2[i], v3 = c1[i], v4 = c2[i];
  float n1 = v1*v1, n2 = v2*v2, n3 = v3*v3, n4 = v4*v4;
#pragma unroll
  for (int o=32;o;o>>=1) {
    n1 += __shfl_xor(n1, o);
    n2 += __shfl_xor(n2, o);
    n3 += __shfl_xor(n3, o);
    n4 += __shfl_xor(n4, o);
  }
  n1 = fmaxf(sqrtf(n1), 1e-12f);
  n2 = fmaxf(sqrtf(n2), 1e-12f);
  n3 = fmaxf(sqrtf(n3), 1e-12f);
  n4 = fmaxf(sqrtf(n4), 1e-12f);
  outg[i] = (a+b+c)*(1.f/3.f)
          + 0.02f*(v1/n1) + 0.02f*(v2/n2)
          + 0.30f*(v3/n3) + 0.30f*(v4/n4);
}

// ===================== host =====================
extern "C" void kernel_launch(void* const* d_in, const int* in_sizes, int n_in,
                              void* d_out, int out_size, void* d_ws, size_t ws_size,
                              hipStream_t stream)
{
  const int*   ui_rows     = (const int*)d_in[0];
  const int*   ui_cols     = (const int*)d_in[1];
  const float* ui_vals     = (const float*)d_in[2];
  const float* image_feats = (const float*)d_in[3];
  const float* text_feats  = (const float*)d_in[4];
  const float* user_feats0 = (const float*)d_in[5];
  const float* item_title  = (const float*)d_in[6];
  const float* W_img = (const float*)d_in[7];
  const float* b_img = (const float*)d_in[8];
  const float* W_txt = (const float*)d_in[9];
  const float* b_txt = (const float*)d_in[10];
  const float* W_usr = (const float*)d_in[11];
  const float* b_usr = (const float*)d_in[12];
  const float* W_itm = (const float*)d_in[13];
  const float* b_itm = (const float*)d_in[14];
  const float* user_id_emb = (const float*)d_in[15];
  const float* item_id_emb = (const float*)d_in[16];
  const int nnz = in_sizes[0];

  float* out = (float*)d_out;
  const size_t OU = (size_t)NU*64, OI = (size_t)NI*64;
  size_t off = 0;
  float* o_ug   = out + off; off += OU;   // u_g
  float* o_ig   = out + off; off += OI;   // i_g
  float* o_ii   = out + off; off += OI;   // image_item
  float* o_ti   = out + off; off += OI;   // text_item
  float* o_iu   = out + off; off += OU;   // image_user
  float* o_tu   = out + off; off += OU;   // text_user
  float* o_ue   = out + off; off += OU;   // usr_e
  float* o_ifo  = out + off; off += OI;   // item_feats_out
  float* o_up   = out + off; off += OU;   // user_prof
  float* o_ip   = out + off; off += OI;   // item_prof
  float* o_ufi  = out + off; off += OU;   // user_feat_from_item
  float* o_mask = out + off; off += NMASK;// mask_nodes (as float)
  float* o_ri   = out + off; off += OI;   // raw_image
  float* o_rt   = out + off; off += OI;   // raw_text
  float* o_rit  = out + off; off += OI;   // raw_item

  // workspace layout (accumulator zone first, memset each call)
  char* wp = (char*)d_ws;
  auto walloc = [&](size_t bytes) -> char* {
    char* r = wp; wp += (bytes + 255) & ~(size_t)255; return r;
  };
  int*   cnt_u = (int*)  walloc((size_t)NU*4);
  int*   cnt_i = (int*)  walloc((size_t)NI*4);
  int*   flag  = (int*)  walloc((size_t)NI*4);
  float* means = (float*)walloc(3*64*4);
  int*   rankA = (int*)  walloc((size_t)NI*4);
  int*   rankB = (int*)  walloc((size_t)NI*4);
  size_t zero_bytes = (size_t)(wp - (char*)d_ws);
  uint32_t* sk    = (uint32_t*)walloc(4*4);
  uint32_t* bits  = (uint32_t*)walloc((size_t)NI*4);
  uint32_t* permA = (uint32_t*)walloc((size_t)NI*4);
  uint32_t* permB = (uint32_t*)walloc((size_t)NI*4);
  int*   ptr_u = (int*)  walloc((size_t)(NU+1)*4);
  int*   ptr_i = (int*)  walloc((size_t)(NI+1)*4);
  int*   cur_u = (int*)  walloc((size_t)NU*4);
  int*   cur_i = (int*)  walloc((size_t)NI*4);
  int*   idx_u = (int*)  walloc((size_t)nnz*4);
  float* val_u = (float*)walloc((size_t)nnz*4);
  int*   idx_i = (int*)  walloc((size_t)nnz*4);
  float* val_i = (float*)walloc((size_t)nnz*4);
  float* u1    = (float*)walloc(OU*4);
  float* i1    = (float*)walloc(OI*4);
  float* pbuf  = (float*)walloc((size_t)4*NI*64*4);  // K-split partials (image worst case)
  size_t used = (size_t)(wp - (char*)d_ws);
  const int ksplit_ok = (used <= ws_size);
  float* mean_img = means, *mean_txt = means + 64, *mean_itm = means + 128;

  hipMemsetAsync(d_ws, 0, zero_bytes, stream);

  // --- mask_nodes: exact JAX permutation(key(42), 20000)[:2000], partitionable path ---
  seed_kernel<<<1, 64, 0, stream>>>(sk);
  dim3 rgrid(cdiv(NI,256), NI/RCH);
  bits_kernel<<<cdiv(NI,256), 256, 0, stream>>>(sk, 0, bits, NI);
  rank_partial_kernel<<<rgrid, 256, 0, stream>>>(bits, rankA, NI);
  scatter_rank_kernel<<<cdiv(NI,256), 256, 0, stream>>>(rankA, nullptr, permA, NI, 1);
  bits_kernel<<<cdiv(NI,256), 256, 0, stream>>>(sk, 1, bits, NI);
  rank_partial_kernel<<<rgrid, 256, 0, stream>>>(bits, rankB, NI);
  scatter_rank_kernel<<<cdiv(NI,256), 256, 0, stream>>>(rankB, permA, permB, NI, 0);
  mask_kernel<<<cdiv(NMASK,256), 256, 0, stream>>>(permB, o_mask, flag);

  // --- raw projections (on UNMASKED inputs); K-split for occupancy ---
  auto gemm = [&](const float* X, const float* W, const float* b, float* o, int N, int K, int nch){
    if (ksplit_ok && nch > 1) {
      int klen = K / nch;
      dim3 g(cdiv(N,64), nch);
      gemm_part_kernel<<<g, 256, 0, stream>>>(X, W, pbuf, N, K, klen);
      gemm_reduce_kernel<<<cdiv(N*64,256), 256, 0, stream>>>(pbuf, b, o, N, nch);
    } else {
      gemm64_kernel<<<cdiv(N,64), 256, 0, stream>>>(X, W, b, o, N, K);
    }
  };
  gemm(image_feats, W_img, b_img, o_ri,  NI, 4096, 4);
  gemm(text_feats,  W_txt, b_txt, o_rt,  NI, 768,  2);
  gemm(item_title,  W_itm, b_itm, o_rit, NI, 1536, 2);
  gemm(user_feats0, W_usr, b_usr, o_ue,  NU, 1536, 2);

  // masked-row projection == column-mean of raw projection (projection is linear)
  colmean_kernel<<<128, 256, 0, stream>>>(o_ri,  mean_img, NI, 1.f/NI);
  colmean_kernel<<<128, 256, 0, stream>>>(o_rt,  mean_txt, NI, 1.f/NI);
  colmean_kernel<<<128, 256, 0, stream>>>(o_rit, mean_itm, NI, 1.f/NI);

  // --- CSR build (rows->users, cols->items) ---
  hist_kernel<<<cdiv(nnz,256), 256, 0, stream>>>(ui_rows, ui_cols, cnt_u, cnt_i, nnz);
  exscan_kernel<<<1, 64, 0, stream>>>(cnt_u, ptr_u, NU);
  exscan_kernel<<<1, 64, 0, stream>>>(cnt_i, ptr_i, NI);
  hipMemcpyAsync(cur_u, ptr_u, (size_t)NU*4, hipMemcpyDeviceToDevice, stream);
  hipMemcpyAsync(cur_i, ptr_i, (size_t)NI*4, hipMemcpyDeviceToDevice, stream);
  scatter_kernel<<<cdiv(nnz,256), 256, 0, stream>>>(ui_rows, ui_cols, ui_vals,
      cur_u, cur_i, idx_u, val_u, idx_i, val_i, nnz);

  const int GU = cdiv(NU,4), GI = cdiv(NI,4);
  // modality propagation (mask substitution fused into gather)
  spmm_kernel<0,1><<<GU,256,0,stream>>>(ptr_u, idx_u, val_u, o_ri,  flag, mean_img, o_iu,  NU);
  spmm_kernel<0,0><<<GI,256,0,stream>>>(ptr_i, idx_i, val_i, o_iu,  nullptr, nullptr, o_ii,  NI);
  spmm_kernel<0,1><<<GU,256,0,stream>>>(ptr_u, idx_u, val_u, o_rt,  flag, mean_txt, o_tu,  NU);
  spmm_kernel<0,0><<<GI,256,0,stream>>>(ptr_i, idx_i, val_i, o_tu,  nullptr, nullptr, o_ti,  NI);
  spmm_kernel<0,1><<<GU,256,0,stream>>>(ptr_u, idx_u, val_u, o_rit, flag, mean_itm, o_ufi, NU);
  spmm_kernel<0,0><<<GI,256,0,stream>>>(ptr_i, idx_i, val_i, o_ufi, nullptr, nullptr, o_ifo, NI);
  // profiles
  spmm_kernel<0,0><<<GI,256,0,stream>>>(ptr_i, idx_i, val_i, o_ue,  nullptr, nullptr, o_ip,  NI);
  spmm_kernel<0,0><<<GU,256,0,stream>>>(ptr_u, idx_u, val_u, o_ip,  nullptr, nullptr, o_up,  NU);
  // LightGCN layers
  spmm_kernel<0,0><<<GU,256,0,stream>>>(ptr_u, idx_u, val_u, item_id_emb, nullptr, nullptr, u1,   NU);
  spmm_kernel<0,0><<<GI,256,0,stream>>>(ptr_i, idx_i, val_i, u1,   nullptr, nullptr, i1,   NI);
  spmm_kernel<1,0><<<GU,256,0,stream>>>(ptr_u, idx_u, val_u, i1,   nullptr, nullptr, o_ug, NU);
  spmm_kernel<1,0><<<GI,256,0,stream>>>(ptr_i, idx_i, val_i, o_ug, nullptr, nullptr, o_ig, NI);

  combine_kernel<<<GU,256,0,stream>>>(user_id_emb, u1, o_ug, o_iu, o_tu, o_up, o_ufi, o_ug, NU);
  combine_kernel<<<GI,256,0,stream>>>(item_id_emb, i1, o_ig, o_ii, o_ti, o_ip, o_ifo, o_ig, NI);
}

// Round 5
// 1481.400 us; speedup vs baseline: 1.9760x; 1.2407x over previous
//
#include <hip/hip_runtime.h>
#include <cstdint>
#include <cstddef>

#define NU 30000
#define NI 20000
#define NMASK 2000

static inline int cdiv(int a, int b){ return (a + b - 1) / b; }

// ===================== threefry-2x32 (exact JAX semantics) =====================
__device__ __forceinline__ uint32_t rotl32(uint32_t x, int r){ return (x<<r)|(x>>(32-r)); }

__device__ __forceinline__ void tf2x32(uint32_t k0, uint32_t k1,
                                       uint32_t x0, uint32_t x1,
                                       uint32_t& o0, uint32_t& o1)
{
  uint32_t k2 = k0 ^ k1 ^ 0x1BD11BDAu;
  x0 += k0; x1 += k1;
#define TFR(r) { x0 += x1; x1 = rotl32(x1,(r)); x1 ^= x0; }
  TFR(13) TFR(15) TFR(26) TFR(6)
  x0 += k1; x1 += k2 + 1u;
  TFR(17) TFR(29) TFR(16) TFR(24)
  x0 += k2; x1 += k0 + 2u;
  TFR(13) TFR(15) TFR(26) TFR(6)
  x0 += k0; x1 += k1 + 3u;
  TFR(17) TFR(29) TFR(16) TFR(24)
  x0 += k1; x1 += k2 + 4u;
  TFR(13) TFR(15) TFR(26) TFR(6)
  x0 += k2; x1 += k0 + 5u;
#undef TFR
  o0 = x0; o1 = x1;
}

// jax_threefry_partitionable=True (default since JAX 0.4.30) semantics.
__global__ void seed_kernel(uint32_t* __restrict__ sk)
{
  if (threadIdx.x == 0 && blockIdx.x == 0) {
    uint32_t c0,c1, s0,s1, t0,t1;
    tf2x32(0u,42u, 0u,0u, c0,c1);   // carried key after round-1 split
    tf2x32(0u,42u, 0u,1u, s0,s1);   // subkey round 1
    tf2x32(c0,c1, 0u,1u, t0,t1);    // subkey round 2
    sk[0]=s0; sk[1]=s1;
    sk[2]=t0; sk[3]=t1;
  }
}

__global__ __launch_bounds__(256) void bits_kernel(const uint32_t* __restrict__ sk, int which,
                                                   uint32_t* __restrict__ bits, int n)
{
  int i = blockIdx.x*256 + threadIdx.x;
  if (i < n) {
    uint32_t o0,o1;
    tf2x32(sk[2*which], sk[2*which+1], 0u, (uint32_t)i, o0,o1);
    bits[i] = o0 ^ o1;
  }
}

// ===================== stable rank sort, j-split for parallelism =====================
#define RCH 2000
__global__ __launch_bounds__(256) void rank_partial_kernel(
    const uint32_t* __restrict__ keys, int* __restrict__ rank, int n)
{
  __shared__ uint32_t lk[RCH];
  int i = blockIdx.x*256 + threadIdx.x;
  int c0 = blockIdx.y * RCH;
  int csz = min(RCH, n - c0);
  for (int j = threadIdx.x; j < csz; j += 256) lk[j] = keys[c0 + j];
  __syncthreads();
  if (i >= n) return;
  uint32_t k = keys[i];
  int r = 0;
  const uint4* lk4 = reinterpret_cast<const uint4*>(lk);
  for (int j = 0; j < csz; j += 16) {
    uint4 a = lk4[(j>>2)+0];
    uint4 b = lk4[(j>>2)+1];
    uint4 c = lk4[(j>>2)+2];
    uint4 d = lk4[(j>>2)+3];
    int g = c0 + j;
    r += (int)(a.x < k) | (int)((a.x == k) & (g + 0  < i));
    r += (int)(a.y < k) | (int)((a.y == k) & (g + 1  < i));
    r += (int)(a.z < k) | (int)((a.z == k) & (g + 2  < i));
    r += (int)(a.w < k) | (int)((a.w == k) & (g + 3  < i));
    r += (int)(b.x < k) | (int)((b.x == k) & (g + 4  < i));
    r += (int)(b.y < k) | (int)((b.y == k) & (g + 5  < i));
    r += (int)(b.z < k) | (int)((b.z == k) & (g + 6  < i));
    r += (int)(b.w < k) | (int)((b.w == k) & (g + 7  < i));
    r += (int)(c.x < k) | (int)((c.x == k) & (g + 8  < i));
    r += (int)(c.y < k) | (int)((c.y == k) & (g + 9  < i));
    r += (int)(c.z < k) | (int)((c.z == k) & (g + 10 < i));
    r += (int)(c.w < k) | (int)((c.w == k) & (g + 11 < i));
    r += (int)(d.x < k) | (int)((d.x == k) & (g + 12 < i));
    r += (int)(d.y < k) | (int)((d.y == k) & (g + 13 < i));
    r += (int)(d.z < k) | (int)((d.z == k) & (g + 14 < i));
    r += (int)(d.w < k) | (int)((d.w == k) & (g + 15 < i));
  }
  atomicAdd(&rank[i], r);
}

__global__ __launch_bounds__(256) void scatter_rank_kernel(
    const int* __restrict__ rank, const uint32_t* __restrict__ vin,
    uint32_t* __restrict__ vout, int n, int ident)
{
  int i = blockIdx.x*256 + threadIdx.x;
  if (i < n) vout[rank[i]] = ident ? (uint32_t)i : vin[i];
}

__global__ __launch_bounds__(256) void mask_kernel(const uint32_t* __restrict__ perm,
                                                   float* __restrict__ mask_out,
                                                   int* __restrict__ flag)
{
  int i = blockIdx.x*256 + threadIdx.x;
  if (i < NMASK) {
    uint32_t v = perm[i];
    mask_out[i] = (float)v;
    flag[v] = 1;
  }
}

// ===================== GEMM: out(N,64) = X(N,K) @ W(64,K)^T + b =====================
// K-split partial GEMM: grid.y = K-chunk, writes partials to pbuf (no bias).
__global__ __launch_bounds__(256) void gemm_part_kernel(
    const float* __restrict__ X, const float* __restrict__ W,
    float* __restrict__ pbuf, int N, int K, int klen)
{
  __shared__ float Xs[32][68];
  __shared__ float Ws[32][68];
  const int tid = threadIdx.x;
  const int row0 = blockIdx.x * 64;
  const int kbeg = blockIdx.y * klen;
  const int tc = (tid & 15) * 4;
  const int tr = ((tid >> 4) & 15) * 4;
  float acc[4][4];
#pragma unroll
  for (int i=0;i<4;i++)
#pragma unroll
    for (int j=0;j<4;j++) acc[i][j]=0.f;

  const int lr = tid >> 3;        // 0..31
  const int lk = (tid & 7) * 4;   // 0..28

  for (int k0 = kbeg; k0 < kbeg + klen; k0 += 32) {
    {
      float4 v0 = make_float4(0.f,0.f,0.f,0.f), v1 = make_float4(0.f,0.f,0.f,0.f);
      int g0 = row0 + lr, g1 = row0 + lr + 32;
      if (g0 < N) v0 = *reinterpret_cast<const float4*>(X + (size_t)g0*K + k0 + lk);
      if (g1 < N) v1 = *reinterpret_cast<const float4*>(X + (size_t)g1*K + k0 + lk);
      Xs[lk+0][lr]=v0.x; Xs[lk+1][lr]=v0.y; Xs[lk+2][lr]=v0.z; Xs[lk+3][lr]=v0.w;
      Xs[lk+0][lr+32]=v1.x; Xs[lk+1][lr+32]=v1.y; Xs[lk+2][lr+32]=v1.z; Xs[lk+3][lr+32]=v1.w;
      float4 w0 = *reinterpret_cast<const float4*>(W + (size_t)lr*K + k0 + lk);
      float4 w1 = *reinterpret_cast<const float4*>(W + (size_t)(lr+32)*K + k0 + lk);
      Ws[lk+0][lr]=w0.x; Ws[lk+1][lr]=w0.y; Ws[lk+2][lr]=w0.z; Ws[lk+3][lr]=w0.w;
      Ws[lk+0][lr+32]=w1.x; Ws[lk+1][lr+32]=w1.y; Ws[lk+2][lr+32]=w1.z; Ws[lk+3][lr+32]=w1.w;
    }
    __syncthreads();
#pragma unroll
    for (int kk = 0; kk < 32; ++kk) {
      float4 xv = *reinterpret_cast<const float4*>(&Xs[kk][tr]);
      float4 wv = *reinterpret_cast<const float4*>(&Ws[kk][tc]);
      float xr[4] = {xv.x,xv.y,xv.z,xv.w};
      float wr[4] = {wv.x,wv.y,wv.z,wv.w};
#pragma unroll
      for (int i=0;i<4;i++)
#pragma unroll
        for (int j=0;j<4;j++)
          acc[i][j] = fmaf(xr[i], wr[j], acc[i][j]);
    }
    __syncthreads();
  }
  float* pb = pbuf + (size_t)blockIdx.y * N * 64;
#pragma unroll
  for (int i=0;i<4;i++) {
    int gr = row0 + tr + i;
    if (gr < N)
      *reinterpret_cast<float4*>(pb + (size_t)gr*64 + tc) =
        make_float4(acc[i][0], acc[i][1], acc[i][2], acc[i][3]);
  }
}

// out[r][c] = bias[c] + sum_ch pbuf[ch][r][c]
__global__ __launch_bounds__(256) void gemm_reduce_kernel(
    const float* __restrict__ pbuf, const float* __restrict__ bias,
    float* __restrict__ out, int N, int nch)
{
  int i = blockIdx.x*256 + threadIdx.x;
  if (i >= N*64) return;
  float s = bias[i & 63];
  for (int ch = 0; ch < nch; ++ch) s += pbuf[(size_t)ch*N*64 + i];
  out[i] = s;
}

// fallback single-pass GEMM (used if workspace too small for partials)
__global__ __launch_bounds__(256) void gemm64_kernel(
    const float* __restrict__ X, const float* __restrict__ W, const float* __restrict__ bias,
    float* __restrict__ out, int N, int K)
{
  __shared__ float Xs[32][68];
  __shared__ float Ws[32][68];
  const int tid = threadIdx.x;
  const int row0 = blockIdx.x * 64;
  const int tc = (tid & 15) * 4;
  const int tr = ((tid >> 4) & 15) * 4;
  float acc[4][4];
#pragma unroll
  for (int i=0;i<4;i++)
#pragma unroll
    for (int j=0;j<4;j++) acc[i][j]=0.f;
  const int lr = tid >> 3;
  const int lk = (tid & 7) * 4;
  for (int k0 = 0; k0 < K; k0 += 32) {
    {
      float4 v0 = make_float4(0.f,0.f,0.f,0.f), v1 = make_float4(0.f,0.f,0.f,0.f);
      int g0 = row0 + lr, g1 = row0 + lr + 32;
      if (g0 < N) v0 = *reinterpret_cast<const float4*>(X + (size_t)g0*K + k0 + lk);
      if (g1 < N) v1 = *reinterpret_cast<const float4*>(X + (size_t)g1*K + k0 + lk);
      Xs[lk+0][lr]=v0.x; Xs[lk+1][lr]=v0.y; Xs[lk+2][lr]=v0.z; Xs[lk+3][lr]=v0.w;
      Xs[lk+0][lr+32]=v1.x; Xs[lk+1][lr+32]=v1.y; Xs[lk+2][lr+32]=v1.z; Xs[lk+3][lr+32]=v1.w;
      float4 w0 = *reinterpret_cast<const float4*>(W + (size_t)lr*K + k0 + lk);
      float4 w1 = *reinterpret_cast<const float4*>(W + (size_t)(lr+32)*K + k0 + lk);
      Ws[lk+0][lr]=w0.x; Ws[lk+1][lr]=w0.y; Ws[lk+2][lr]=w0.z; Ws[lk+3][lr]=w0.w;
      Ws[lk+0][lr+32]=w1.x; Ws[lk+1][lr+32]=w1.y; Ws[lk+2][lr+32]=w1.z; Ws[lk+3][lr+32]=w1.w;
    }
    __syncthreads();
#pragma unroll
    for (int kk = 0; kk < 32; ++kk) {
      float4 xv = *reinterpret_cast<const float4*>(&Xs[kk][tr]);
      float4 wv = *reinterpret_cast<const float4*>(&Ws[kk][tc]);
      float xr[4] = {xv.x,xv.y,xv.z,xv.w};
      float wr[4] = {wv.x,wv.y,wv.z,wv.w};
#pragma unroll
      for (int i=0;i<4;i++)
#pragma unroll
        for (int j=0;j<4;j++)
          acc[i][j] = fmaf(xr[i], wr[j], acc[i][j]);
    }
    __syncthreads();
  }
#pragma unroll
  for (int i=0;i<4;i++) {
    int gr = row0 + tr + i;
    if (gr < N) {
      float4 o;
      o.x = acc[i][0] + bias[tc+0];
      o.y = acc[i][1] + bias[tc+1];
      o.z = acc[i][2] + bias[tc+2];
      o.w = acc[i][3] + bias[tc+3];
      *reinterpret_cast<float4*>(out + (size_t)gr*64 + tc) = o;
    }
  }
}

// column mean of (n,64) matrix into mean[64] (mean pre-zeroed)
__global__ __launch_bounds__(256) void colmean_kernel(const float* __restrict__ a,
                                                      float* __restrict__ mean,
                                                      int n, float inv_n)
{
  __shared__ float red[256];
  int lane = threadIdx.x & 63;
  int w = threadIdx.x >> 6;
  float s = 0.f;
  for (int r = blockIdx.x*4 + w; r < n; r += gridDim.x*4)
    s += a[(size_t)r*64 + lane];
  red[threadIdx.x] = s;
  __syncthreads();
  if (threadIdx.x < 64) {
    float t = red[lane] + red[64+lane] + red[128+lane] + red[192+lane];
    atomicAdd(&mean[lane], t * inv_n);
  }
}

// ===================== CSR build =====================
__global__ __launch_bounds__(256) void hist_kernel(const int* __restrict__ rows,
                                                   const int* __restrict__ cols,
                                                   int* __restrict__ cu, int* __restrict__ ci, int nnz)
{
  int k = blockIdx.x*256 + threadIdx.x;
  if (k < nnz) { atomicAdd(&cu[rows[k]], 1); atomicAdd(&ci[cols[k]], 1); }
}

// ---- 3-phase parallel exclusive scan ----
// phase 1: per-block exclusive scan + block total
__global__ __launch_bounds__(256) void scan_block_kernel(
    const int* __restrict__ cnt, int* __restrict__ part, int* __restrict__ bsum, int n)
{
  __shared__ int wsum[4];
  int i = blockIdx.x*256 + threadIdx.x;
  int lane = threadIdx.x & 63;
  int w = threadIdx.x >> 6;
  int v = (i < n) ? cnt[i] : 0;
  int s = v;
#pragma unroll
  for (int off = 1; off < 64; off <<= 1) {
    int t = __shfl_up(s, off);
    if (lane >= off) s += t;
  }
  if (lane == 63) wsum[w] = s;
  __syncthreads();
  int wo = 0;
#pragma unroll
  for (int k = 0; k < 4; ++k) if (k < w) wo += wsum[k];
  if (i < n) part[i] = wo + s - v;
  if (threadIdx.x == 255) bsum[blockIdx.x] = wo + s;
}

// single-wave scan of block sums (nb <= ~128) — reused from before
__global__ __launch_bounds__(64) void exscan_kernel(const int* __restrict__ cnt,
                                                    int* __restrict__ ptr, int n)
{
  int lane = threadIdx.x;
  int carry = 0;
  for (int base = 0; base < n; base += 64) {
    int i = base + lane;
    int v = (i < n) ? cnt[i] : 0;
    int s = v;
#pragma unroll
    for (int off = 1; off < 64; off <<= 1) {
      int t = __shfl_up(s, off);
      if (lane >= off) s += t;
    }
    if (i < n) ptr[i] = carry + s - v;
    carry += __shfl(s, 63);
  }
  if (lane == 0) ptr[n] = carry;
}

// phase 3: add block offsets, emit ptr[n]
__global__ __launch_bounds__(256) void scan_add_kernel(
    const int* __restrict__ part, const int* __restrict__ bptr,
    int* __restrict__ ptr, int n, int nb)
{
  int i = blockIdx.x*256 + threadIdx.x;
  if (i < n) ptr[i] = part[i] + bptr[blockIdx.x];
  if (i == 0) ptr[n] = bptr[nb];
}

__global__ __launch_bounds__(256) void scatter_kernel(
    const int* __restrict__ rows, const int* __restrict__ cols, const float* __restrict__ vals,
    int* __restrict__ cur_u, int* __restrict__ cur_i,
    int* __restrict__ idx_u, float* __restrict__ val_u,
    int* __restrict__ idx_i, float* __restrict__ val_i, int nnz)
{
  int k = blockIdx.x*256 + threadIdx.x;
  if (k < nnz) {
    int r = rows[k], c = cols[k];
    float v = vals[k];
    int pu = atomicAdd(&cur_u[r], 1);
    idx_u[pu] = c; val_u[pu] = v;
    int pi = atomicAdd(&cur_i[c], 1);
    idx_i[pi] = r; val_i[pi] = v;
  }
}

// ===================== SpMM (one wave per row, lane = embedding column) =====================
template<int SOFTMAX, int MASKSUB>
__global__ __launch_bounds__(256) void spmm_kernel(
    const int* __restrict__ ptr, const int* __restrict__ idx, const float* __restrict__ val,
    const float* __restrict__ x, const int* __restrict__ flag, const float* __restrict__ sub,
    float* __restrict__ out, int nrows)
{
  int row = blockIdx.x*4 + (threadIdx.x >> 6);
  int lane = threadIdx.x & 63;
  if (row >= nrows) return;
  int p0 = ptr[row], p1 = ptr[row+1];
  float acc = 0.f;
  float subv = 0.f;
  if (MASKSUB) subv = sub[lane];
  for (int p = p0; p < p1; ++p) {
    int j = idx[p];
    float v = val[p];
    float xv = x[(size_t)j*64 + lane];
    if (MASKSUB) { if (flag[j]) xv = subv; }
    acc = fmaf(v, xv, acc);
  }
  if (SOFTMAX) {
    float m = acc;
#pragma unroll
    for (int o=32;o;o>>=1) m = fmaxf(m, __shfl_xor(m, o));
    float e = expf(acc - m);
    float s = e;
#pragma unroll
    for (int o=32;o;o>>=1) s += __shfl_xor(s, o);
    acc = e / s;
  }
  out[(size_t)row*64 + lane] = acc;
}

// ===================== final combine =====================
__global__ __launch_bounds__(256) void combine_kernel(
    const float* e0, const float* e1, const float* e2,
    const float* m1, const float* m2,
    const float* c1, const float* c2,
    float* outg, int n)
{
  int row = blockIdx.x*4 + (threadIdx.x >> 6);
  int lane = threadIdx.x & 63;
  if (row >= n) return;
  size_t i = (size_t)row*64 + lane;
  float a = e0[i], b = e1[i], c = e2[i];
  float v1 = m1[i], v2 = m2[i], v3 = c1[i], v4 = c2[i];
  float n1 = v1*v1, n2 = v2*v2, n3 = v3*v3, n4 = v4*v4;
#pragma unroll
  for (int o=32;o;o>>=1) {
    n1 += __shfl_xor(n1, o);
    n2 += __shfl_xor(n2, o);
    n3 += __shfl_xor(n3, o);
    n4 += __shfl_xor(n4, o);
  }
  n1 = fmaxf(sqrtf(n1), 1e-12f);
  n2 = fmaxf(sqrtf(n2), 1e-12f);
  n3 = fmaxf(sqrtf(n3), 1e-12f);
  n4 = fmaxf(sqrtf(n4), 1e-12f);
  outg[i] = (a+b+c)*(1.f/3.f)
          + 0.02f*(v1/n1) + 0.02f*(v2/n2)
          + 0.30f*(v3/n3) + 0.30f*(v4/n4);
}

// ===================== host =====================
extern "C" void kernel_launch(void* const* d_in, const int* in_sizes, int n_in,
                              void* d_out, int out_size, void* d_ws, size_t ws_size,
                              hipStream_t stream)
{
  const int*   ui_rows     = (const int*)d_in[0];
  const int*   ui_cols     = (const int*)d_in[1];
  const float* ui_vals     = (const float*)d_in[2];
  const float* image_feats = (const float*)d_in[3];
  const float* text_feats  = (const float*)d_in[4];
  const float* user_feats0 = (const float*)d_in[5];
  const float* item_title  = (const float*)d_in[6];
  const float* W_img = (const float*)d_in[7];
  const float* b_img = (const float*)d_in[8];
  const float* W_txt = (const float*)d_in[9];
  const float* b_txt = (const float*)d_in[10];
  const float* W_usr = (const float*)d_in[11];
  const float* b_usr = (const float*)d_in[12];
  const float* W_itm = (const float*)d_in[13];
  const float* b_itm = (const float*)d_in[14];
  const float* user_id_emb = (const float*)d_in[15];
  const float* item_id_emb = (const float*)d_in[16];
  const int nnz = in_sizes[0];

  float* out = (float*)d_out;
  const size_t OU = (size_t)NU*64, OI = (size_t)NI*64;
  size_t off = 0;
  float* o_ug   = out + off; off += OU;   // u_g
  float* o_ig   = out + off; off += OI;   // i_g
  float* o_ii   = out + off; off += OI;   // image_item
  float* o_ti   = out + off; off += OI;   // text_item
  float* o_iu   = out + off; off += OU;   // image_user
  float* o_tu   = out + off; off += OU;   // text_user
  float* o_ue   = out + off; off += OU;   // usr_e
  float* o_ifo  = out + off; off += OI;   // item_feats_out
  float* o_up   = out + off; off += OU;   // user_prof
  float* o_ip   = out + off; off += OI;   // item_prof
  float* o_ufi  = out + off; off += OU;   // user_feat_from_item
  float* o_mask = out + off; off += NMASK;// mask_nodes (as float)
  float* o_ri   = out + off; off += OI;   // raw_image
  float* o_rt   = out + off; off += OI;   // raw_text
  float* o_rit  = out + off; off += OI;   // raw_item

  // workspace layout (accumulator zone first, memset each call)
  char* wp = (char*)d_ws;
  auto walloc = [&](size_t bytes) -> char* {
    char* r = wp; wp += (bytes + 255) & ~(size_t)255; return r;
  };
  int*   cnt_u = (int*)  walloc((size_t)NU*4);
  int*   cnt_i = (int*)  walloc((size_t)NI*4);
  int*   flag  = (int*)  walloc((size_t)NI*4);
  float* means = (float*)walloc(3*64*4);
  int*   rankA = (int*)  walloc((size_t)NI*4);
  int*   rankB = (int*)  walloc((size_t)NI*4);
  size_t zero_bytes = (size_t)(wp - (char*)d_ws);
  uint32_t* sk    = (uint32_t*)walloc(4*4);
  uint32_t* bits  = (uint32_t*)walloc((size_t)NI*4);
  uint32_t* permA = (uint32_t*)walloc((size_t)NI*4);
  uint32_t* permB = (uint32_t*)walloc((size_t)NI*4);
  int*   ptr_u = (int*)  walloc((size_t)(NU+1)*4);
  int*   ptr_i = (int*)  walloc((size_t)(NI+1)*4);
  int*   cur_u = (int*)  walloc((size_t)NU*4);
  int*   cur_i = (int*)  walloc((size_t)NI*4);
  int*   idx_u = (int*)  walloc((size_t)nnz*4);
  float* val_u = (float*)walloc((size_t)nnz*4);
  int*   idx_i = (int*)  walloc((size_t)nnz*4);
  float* val_i = (float*)walloc((size_t)nnz*4);
  float* u1    = (float*)walloc(OU*4);
  float* i1    = (float*)walloc(OI*4);
  int*   part  = (int*)  walloc((size_t)NU*4);     // scan partials
  int*   bsum  = (int*)  walloc(256*4);            // block sums
  int*   bptr  = (int*)  walloc(257*4);            // scanned block sums
  float* pbuf  = (float*)walloc((size_t)4*NI*64*4);// K-split partials (image worst case)
  size_t used = (size_t)(wp - (char*)d_ws);
  const int ksplit_ok = (used <= ws_size);
  float* mean_img = means, *mean_txt = means + 64, *mean_itm = means + 128;

  hipMemsetAsync(d_ws, 0, zero_bytes, stream);

  // --- mask_nodes: exact JAX permutation(key(42), 20000)[:2000], partitionable path ---
  seed_kernel<<<1, 64, 0, stream>>>(sk);
  dim3 rgrid(cdiv(NI,256), NI/RCH);
  bits_kernel<<<cdiv(NI,256), 256, 0, stream>>>(sk, 0, bits, NI);
  rank_partial_kernel<<<rgrid, 256, 0, stream>>>(bits, rankA, NI);
  scatter_rank_kernel<<<cdiv(NI,256), 256, 0, stream>>>(rankA, nullptr, permA, NI, 1);
  bits_kernel<<<cdiv(NI,256), 256, 0, stream>>>(sk, 1, bits, NI);
  rank_partial_kernel<<<rgrid, 256, 0, stream>>>(bits, rankB, NI);
  scatter_rank_kernel<<<cdiv(NI,256), 256, 0, stream>>>(rankB, permA, permB, NI, 0);
  mask_kernel<<<cdiv(NMASK,256), 256, 0, stream>>>(permB, o_mask, flag);

  // --- raw projections (on UNMASKED inputs); K-split for occupancy ---
  auto gemm = [&](const float* X, const float* W, const float* b, float* o, int N, int K, int nch){
    if (ksplit_ok && nch > 1) {
      int klen = K / nch;
      dim3 g(cdiv(N,64), nch);
      gemm_part_kernel<<<g, 256, 0, stream>>>(X, W, pbuf, N, K, klen);
      gemm_reduce_kernel<<<cdiv(N*64,256), 256, 0, stream>>>(pbuf, b, o, N, nch);
    } else {
      gemm64_kernel<<<cdiv(N,64), 256, 0, stream>>>(X, W, b, o, N, K);
    }
  };
  gemm(image_feats, W_img, b_img, o_ri,  NI, 4096, 4);
  gemm(text_feats,  W_txt, b_txt, o_rt,  NI, 768,  2);
  gemm(item_title,  W_itm, b_itm, o_rit, NI, 1536, 2);
  gemm(user_feats0, W_usr, b_usr, o_ue,  NU, 1536, 2);

  // masked-row projection == column-mean of raw projection (projection is linear)
  colmean_kernel<<<128, 256, 0, stream>>>(o_ri,  mean_img, NI, 1.f/NI);
  colmean_kernel<<<128, 256, 0, stream>>>(o_rt,  mean_txt, NI, 1.f/NI);
  colmean_kernel<<<128, 256, 0, stream>>>(o_rit, mean_itm, NI, 1.f/NI);

  // --- CSR build (rows->users, cols->items) ---
  hist_kernel<<<cdiv(nnz,256), 256, 0, stream>>>(ui_rows, ui_cols, cnt_u, cnt_i, nnz);
  {
    int nbu = cdiv(NU,256);
    scan_block_kernel<<<nbu, 256, 0, stream>>>(cnt_u, part, bsum, NU);
    exscan_kernel<<<1, 64, 0, stream>>>(bsum, bptr, nbu);
    scan_add_kernel<<<nbu, 256, 0, stream>>>(part, bptr, ptr_u, NU, nbu);
    int nbi = cdiv(NI,256);
    scan_block_kernel<<<nbi, 256, 0, stream>>>(cnt_i, part, bsum, NI);
    exscan_kernel<<<1, 64, 0, stream>>>(bsum, bptr, nbi);
    scan_add_kernel<<<nbi, 256, 0, stream>>>(part, bptr, ptr_i, NI, nbi);
  }
  hipMemcpyAsync(cur_u, ptr_u, (size_t)NU*4, hipMemcpyDeviceToDevice, stream);
  hipMemcpyAsync(cur_i, ptr_i, (size_t)NI*4, hipMemcpyDeviceToDevice, stream);
  scatter_kernel<<<cdiv(nnz,256), 256, 0, stream>>>(ui_rows, ui_cols, ui_vals,
      cur_u, cur_i, idx_u, val_u, idx_i, val_i, nnz);

  const int GU = cdiv(NU,4), GI = cdiv(NI,4);
  // modality propagation (mask substitution fused into gather)
  spmm_kernel<0,1><<<GU,256,0,stream>>>(ptr_u, idx_u, val_u, o_ri,  flag, mean_img, o_iu,  NU);
  spmm_kernel<0,0><<<GI,256,0,stream>>>(ptr_i, idx_i, val_i, o_iu,  nullptr, nullptr, o_ii,  NI);
  spmm_kernel<0,1><<<GU,256,0,stream>>>(ptr_u, idx_u, val_u, o_rt,  flag, mean_txt, o_tu,  NU);
  spmm_kernel<0,0><<<GI,256,0,stream>>>(ptr_i, idx_i, val_i, o_tu,  nullptr, nullptr, o_ti,  NI);
  spmm_kernel<0,1><<<GU,256,0,stream>>>(ptr_u, idx_u, val_u, o_rit, flag, mean_itm, o_ufi, NU);
  spmm_kernel<0,0><<<GI,256,0,stream>>>(ptr_i, idx_i, val_i, o_ufi, nullptr, nullptr, o_ifo, NI);
  // profiles
  spmm_kernel<0,0><<<GI,256,0,stream>>>(ptr_i, idx_i, val_i, o_ue,  nullptr, nullptr, o_ip,  NI);
  spmm_kernel<0,0><<<GU,256,0,stream>>>(ptr_u, idx_u, val_u, o_ip,  nullptr, nullptr, o_up,  NU);
  // LightGCN layers
  spmm_kernel<0,0><<<GU,256,0,stream>>>(ptr_u, idx_u, val_u, item_id_emb, nullptr, nullptr, u1,   NU);
  spmm_kernel<0,0><<<GI,256,0,stream>>>(ptr_i, idx_i, val_i, u1,   nullptr, nullptr, i1,   NI);
  spmm_kernel<1,0><<<GU,256,0,stream>>>(ptr_u, idx_u, val_u, i1,   nullptr, nullptr, o_ug, NU);
  spmm_kernel<1,0><<<GI,256,0,stream>>>(ptr_i, idx_i, val_i, o_ug, nullptr, nullptr, o_ig, NI);

  combine_kernel<<<GU,256,0,stream>>>(user_id_emb, u1, o_ug, o_iu, o_tu, o_up, o_ufi, o_ug, NU);
  combine_kernel<<<GI,256,0,stream>>>(item_id_emb, i1, o_ig, o_ii, o_ti, o_ip, o_ifo, o_ig, NI);
}

// Round 6
// 937.842 us; speedup vs baseline: 3.1212x; 1.5796x over previous
//
#include <hip/hip_runtime.h>
#include <cstdint>
#include <cstddef>

#define NU 30000
#define NI 20000
#define NMASK 2000

static inline int cdiv(int a, int b){ return (a + b - 1) / b; }

typedef __attribute__((ext_vector_type(8))) short bf16x8;
typedef __attribute__((ext_vector_type(4))) float f32x4;

// ===================== threefry-2x32 (exact JAX semantics) =====================
__device__ __forceinline__ uint32_t rotl32(uint32_t x, int r){ return (x<<r)|(x>>(32-r)); }

__device__ __forceinline__ void tf2x32(uint32_t k0, uint32_t k1,
                                       uint32_t x0, uint32_t x1,
                                       uint32_t& o0, uint32_t& o1)
{
  uint32_t k2 = k0 ^ k1 ^ 0x1BD11BDAu;
  x0 += k0; x1 += k1;
#define TFR(r) { x0 += x1; x1 = rotl32(x1,(r)); x1 ^= x0; }
  TFR(13) TFR(15) TFR(26) TFR(6)
  x0 += k1; x1 += k2 + 1u;
  TFR(17) TFR(29) TFR(16) TFR(24)
  x0 += k2; x1 += k0 + 2u;
  TFR(13) TFR(15) TFR(26) TFR(6)
  x0 += k0; x1 += k1 + 3u;
  TFR(17) TFR(29) TFR(16) TFR(24)
  x0 += k1; x1 += k2 + 4u;
  TFR(13) TFR(15) TFR(26) TFR(6)
  x0 += k2; x1 += k0 + 5u;
#undef TFR
  o0 = x0; o1 = x1;
}

// jax_threefry_partitionable=True (default since JAX 0.4.30) semantics.
__global__ void seed_kernel(uint32_t* __restrict__ sk)
{
  if (threadIdx.x == 0 && blockIdx.x == 0) {
    uint32_t c0,c1, s0,s1, t0,t1;
    tf2x32(0u,42u, 0u,0u, c0,c1);   // carried key after round-1 split
    tf2x32(0u,42u, 0u,1u, s0,s1);   // subkey round 1
    tf2x32(c0,c1, 0u,1u, t0,t1);    // subkey round 2
    sk[0]=s0; sk[1]=s1;
    sk[2]=t0; sk[3]=t1;
  }
}

__global__ __launch_bounds__(256) void bits_kernel(const uint32_t* __restrict__ sk, int which,
                                                   uint32_t* __restrict__ bits, int n)
{
  int i = blockIdx.x*256 + threadIdx.x;
  if (i < n) {
    uint32_t o0,o1;
    tf2x32(sk[2*which], sk[2*which+1], 0u, (uint32_t)i, o0,o1);
    bits[i] = o0 ^ o1;
  }
}

// ===================== stable rank sort, j-split for parallelism =====================
#define RCH 2000
__global__ __launch_bounds__(256) void rank_partial_kernel(
    const uint32_t* __restrict__ keys, int* __restrict__ rank, int n)
{
  __shared__ uint32_t lk[RCH];
  int i = blockIdx.x*256 + threadIdx.x;
  int c0 = blockIdx.y * RCH;
  int csz = min(RCH, n - c0);
  for (int j = threadIdx.x; j < csz; j += 256) lk[j] = keys[c0 + j];
  __syncthreads();
  if (i >= n) return;
  uint32_t k = keys[i];
  int r = 0;
  const uint4* lk4 = reinterpret_cast<const uint4*>(lk);
  for (int j = 0; j < csz; j += 16) {
    uint4 a = lk4[(j>>2)+0];
    uint4 b = lk4[(j>>2)+1];
    uint4 c = lk4[(j>>2)+2];
    uint4 d = lk4[(j>>2)+3];
    int g = c0 + j;
    r += (int)(a.x < k) | (int)((a.x == k) & (g + 0  < i));
    r += (int)(a.y < k) | (int)((a.y == k) & (g + 1  < i));
    r += (int)(a.z < k) | (int)((a.z == k) & (g + 2  < i));
    r += (int)(a.w < k) | (int)((a.w == k) & (g + 3  < i));
    r += (int)(b.x < k) | (int)((b.x == k) & (g + 4  < i));
    r += (int)(b.y < k) | (int)((b.y == k) & (g + 5  < i));
    r += (int)(b.z < k) | (int)((b.z == k) & (g + 6  < i));
    r += (int)(b.w < k) | (int)((b.w == k) & (g + 7  < i));
    r += (int)(c.x < k) | (int)((c.x == k) & (g + 8  < i));
    r += (int)(c.y < k) | (int)((c.y == k) & (g + 9  < i));
    r += (int)(c.z < k) | (int)((c.z == k) & (g + 10 < i));
    r += (int)(c.w < k) | (int)((c.w == k) & (g + 11 < i));
    r += (int)(d.x < k) | (int)((d.x == k) & (g + 12 < i));
    r += (int)(d.y < k) | (int)((d.y == k) & (g + 13 < i));
    r += (int)(d.z < k) | (int)((d.z == k) & (g + 14 < i));
    r += (int)(d.w < k) | (int)((d.w == k) & (g + 15 < i));
  }
  atomicAdd(&rank[i], r);
}

__global__ __launch_bounds__(256) void scatter_rank_kernel(
    const int* __restrict__ rank, const uint32_t* __restrict__ vin,
    uint32_t* __restrict__ vout, int n, int ident)
{
  int i = blockIdx.x*256 + threadIdx.x;
  if (i < n) vout[rank[i]] = ident ? (uint32_t)i : vin[i];
}

__global__ __launch_bounds__(256) void mask_kernel(const uint32_t* __restrict__ perm,
                                                   float* __restrict__ mask_out,
                                                   int* __restrict__ flag)
{
  int i = blockIdx.x*256 + threadIdx.x;
  if (i < NMASK) {
    uint32_t v = perm[i];
    mask_out[i] = (float)v;
    flag[v] = 1;
  }
}

// ===================== MFMA GEMM: out(N,64) = X(N,K) @ W(64,K)^T =====================
// f32 inputs converted to bf16 (RNE), f32 accumulate via mfma_f32_16x16x32_bf16.
// 64x64 tile, K-chunk 64, K-split over grid.y writes partials to pbuf.
__device__ __forceinline__ ushort f2bf(float f){
  union { float f; uint32_t u; } c; c.f = f;
  uint32_t u = c.u;
  return (ushort)((u + 0x7fffu + ((u >> 16) & 1u)) >> 16);
}

__global__ __launch_bounds__(256) void gemm_mfma_kernel(
    const float* __restrict__ X, const float* __restrict__ W,
    float* __restrict__ pbuf, int N, int K, int klen)
{
  __shared__ ushort Xs[64][72];   // +8 pad: 144B row stride -> 2-way banks only
  __shared__ ushort Ws[64][72];
  const int tid = threadIdx.x;
  const int row0 = blockIdx.x * 64;
  const int kbeg = blockIdx.y * klen;
  const int lane = tid & 63;
  const int wr = tid >> 6;          // wave id -> 16-row tile
  const int lrow = lane & 15;
  const int kslot = lane >> 4;      // 0..3
  f32x4 acc[4] = {f32x4{0,0,0,0},f32x4{0,0,0,0},f32x4{0,0,0,0},f32x4{0,0,0,0}};

  const int sr = tid >> 4;          // staging row 0..15 (+16i)
  const int sc = (tid & 15) * 4;    // staging col (floats)

  for (int k0 = kbeg; k0 < kbeg + klen; k0 += 64) {
#pragma unroll
    for (int i = 0; i < 4; ++i) {
      int r = sr + 16*i;
      int gr = row0 + r;
      float4 v = make_float4(0.f,0.f,0.f,0.f);
      if (gr < N) v = *reinterpret_cast<const float4*>(X + (size_t)gr*K + k0 + sc);
      ushort4 h; h.x=f2bf(v.x); h.y=f2bf(v.y); h.z=f2bf(v.z); h.w=f2bf(v.w);
      *reinterpret_cast<ushort4*>(&Xs[r][sc]) = h;
      float4 w = *reinterpret_cast<const float4*>(W + (size_t)r*K + k0 + sc);
      ushort4 hw; hw.x=f2bf(w.x); hw.y=f2bf(w.y); hw.z=f2bf(w.z); hw.w=f2bf(w.w);
      *reinterpret_cast<ushort4*>(&Ws[r][sc]) = hw;
    }
    __syncthreads();
#pragma unroll
    for (int ks = 0; ks < 2; ++ks) {
      int kb = ks*32 + kslot*8;
      bf16x8 af = *reinterpret_cast<const bf16x8*>(&Xs[wr*16 + lrow][kb]);
#pragma unroll
      for (int ct = 0; ct < 4; ++ct) {
        bf16x8 bfr = *reinterpret_cast<const bf16x8*>(&Ws[ct*16 + lrow][kb]);
        acc[ct] = __builtin_amdgcn_mfma_f32_16x16x32_bf16(af, bfr, acc[ct], 0, 0, 0);
      }
    }
    __syncthreads();
  }
  float* pb = pbuf + (size_t)blockIdx.y * N * 64;
#pragma unroll
  for (int ct = 0; ct < 4; ++ct)
#pragma unroll
    for (int j = 0; j < 4; ++j) {
      int gr = row0 + wr*16 + kslot*4 + j;   // C/D: row=(lane>>4)*4+reg, col=lane&15
      if (gr < N) pb[(size_t)gr*64 + ct*16 + lrow] = acc[ct][j];
    }
}

// out[r][c] = bias[c] + sum_ch pbuf[ch][r][c]
__global__ __launch_bounds__(256) void gemm_reduce_kernel(
    const float* __restrict__ pbuf, const float* __restrict__ bias,
    float* __restrict__ out, int N, int nch)
{
  int i = blockIdx.x*256 + threadIdx.x;
  if (i >= N*64) return;
  float s = bias[i & 63];
  for (int ch = 0; ch < nch; ++ch) s += pbuf[(size_t)ch*N*64 + i];
  out[i] = s;
}

// column mean of (n,64) matrix into mean[64] (mean pre-zeroed)
__global__ __launch_bounds__(256) void colmean_kernel(const float* __restrict__ a,
                                                      float* __restrict__ mean,
                                                      int n, float inv_n)
{
  __shared__ float red[256];
  int lane = threadIdx.x & 63;
  int w = threadIdx.x >> 6;
  float s = 0.f;
  for (int r = blockIdx.x*4 + w; r < n; r += gridDim.x*4)
    s += a[(size_t)r*64 + lane];
  red[threadIdx.x] = s;
  __syncthreads();
  if (threadIdx.x < 64) {
    float t = red[lane] + red[64+lane] + red[128+lane] + red[192+lane];
    atomicAdd(&mean[lane], t * inv_n);
  }
}

// ===================== CSR build =====================
__global__ __launch_bounds__(256) void hist_kernel(const int* __restrict__ rows,
                                                   const int* __restrict__ cols,
                                                   int* __restrict__ cu, int* __restrict__ ci, int nnz)
{
  int k = blockIdx.x*256 + threadIdx.x;
  if (k < nnz) { atomicAdd(&cu[rows[k]], 1); atomicAdd(&ci[cols[k]], 1); }
}

__global__ __launch_bounds__(256) void scan_block_kernel(
    const int* __restrict__ cnt, int* __restrict__ part, int* __restrict__ bsum, int n)
{
  __shared__ int wsum[4];
  int i = blockIdx.x*256 + threadIdx.x;
  int lane = threadIdx.x & 63;
  int w = threadIdx.x >> 6;
  int v = (i < n) ? cnt[i] : 0;
  int s = v;
#pragma unroll
  for (int off = 1; off < 64; off <<= 1) {
    int t = __shfl_up(s, off);
    if (lane >= off) s += t;
  }
  if (lane == 63) wsum[w] = s;
  __syncthreads();
  int wo = 0;
#pragma unroll
  for (int k = 0; k < 4; ++k) if (k < w) wo += wsum[k];
  if (i < n) part[i] = wo + s - v;
  if (threadIdx.x == 255) bsum[blockIdx.x] = wo + s;
}

__global__ __launch_bounds__(64) void exscan_kernel(const int* __restrict__ cnt,
                                                    int* __restrict__ ptr, int n)
{
  int lane = threadIdx.x;
  int carry = 0;
  for (int base = 0; base < n; base += 64) {
    int i = base + lane;
    int v = (i < n) ? cnt[i] : 0;
    int s = v;
#pragma unroll
    for (int off = 1; off < 64; off <<= 1) {
      int t = __shfl_up(s, off);
      if (lane >= off) s += t;
    }
    if (i < n) ptr[i] = carry + s - v;
    carry += __shfl(s, 63);
  }
  if (lane == 0) ptr[n] = carry;
}

__global__ __launch_bounds__(256) void scan_add_kernel(
    const int* __restrict__ part, const int* __restrict__ bptr,
    int* __restrict__ ptr, int n, int nb)
{
  int i = blockIdx.x*256 + threadIdx.x;
  if (i < n) ptr[i] = part[i] + bptr[blockIdx.x];
  if (i == 0) ptr[n] = bptr[nb];
}

__global__ __launch_bounds__(256) void scatter_kernel(
    const int* __restrict__ rows, const int* __restrict__ cols, const float* __restrict__ vals,
    int* __restrict__ cur_u, int* __restrict__ cur_i,
    int* __restrict__ idx_u, float* __restrict__ val_u,
    int* __restrict__ idx_i, float* __restrict__ val_i, int nnz)
{
  int k = blockIdx.x*256 + threadIdx.x;
  if (k < nnz) {
    int r = rows[k], c = cols[k];
    float v = vals[k];
    int pu = atomicAdd(&cur_u[r], 1);
    idx_u[pu] = c; val_u[pu] = v;
    int pi = atomicAdd(&cur_i[c], 1);
    idx_i[pi] = r; val_i[pi] = v;
  }
}

// ===================== fused SpMMs (one wave per row, lane = embedding col) =====================
// user round 1: 4 sources over idx_u (3 mask-substituted + id-emb)
__global__ __launch_bounds__(256) void spmm_user1_kernel(
    const int* __restrict__ ptr, const int* __restrict__ idx, const float* __restrict__ val,
    const float* __restrict__ ri, const float* __restrict__ rt, const float* __restrict__ rit,
    const float* __restrict__ idemb, const int* __restrict__ flag, const float* __restrict__ means,
    float* __restrict__ iu, float* __restrict__ tu, float* __restrict__ ufi, float* __restrict__ u1,
    int nrows)
{
  int row = blockIdx.x*4 + (threadIdx.x >> 6);
  int lane = threadIdx.x & 63;
  if (row >= nrows) return;
  int p0 = ptr[row], p1 = ptr[row+1];
  float m0 = means[lane], m1 = means[64+lane], m2 = means[128+lane];
  float a0=0.f, a1=0.f, a2=0.f, a3=0.f;
  for (int p = p0; p < p1; ++p) {
    int j = idx[p]; float v = val[p];
    size_t b = (size_t)j*64 + lane;
    int f = flag[j];
    float x0 = ri[b], x1 = rt[b], x2 = rit[b], x3 = idemb[b];
    if (f) { x0 = m0; x1 = m1; x2 = m2; }
    a0 = fmaf(v, x0, a0); a1 = fmaf(v, x1, a1);
    a2 = fmaf(v, x2, a2); a3 = fmaf(v, x3, a3);
  }
  size_t o = (size_t)row*64 + lane;
  iu[o]=a0; tu[o]=a1; ufi[o]=a2; u1[o]=a3;
}

// item round 1: 5 sources over idx_i
__global__ __launch_bounds__(256) void spmm_item1_kernel(
    const int* __restrict__ ptr, const int* __restrict__ idx, const float* __restrict__ val,
    const float* __restrict__ iu, const float* __restrict__ tu, const float* __restrict__ ufi,
    const float* __restrict__ u1, const float* __restrict__ ue,
    float* __restrict__ ii, float* __restrict__ ti, float* __restrict__ ifo,
    float* __restrict__ i1, float* __restrict__ ip, int nrows)
{
  int row = blockIdx.x*4 + (threadIdx.x >> 6);
  int lane = threadIdx.x & 63;
  if (row >= nrows) return;
  int p0 = ptr[row], p1 = ptr[row+1];
  float a0=0.f, a1=0.f, a2=0.f, a3=0.f, a4=0.f;
  for (int p = p0; p < p1; ++p) {
    int j = idx[p]; float v = val[p];
    size_t b = (size_t)j*64 + lane;
    float x0 = iu[b], x1 = tu[b], x2 = ufi[b], x3 = u1[b], x4 = ue[b];
    a0 = fmaf(v, x0, a0); a1 = fmaf(v, x1, a1); a2 = fmaf(v, x2, a2);
    a3 = fmaf(v, x3, a3); a4 = fmaf(v, x4, a4);
  }
  size_t o = (size_t)row*64 + lane;
  ii[o]=a0; ti[o]=a1; ifo[o]=a2; i1[o]=a3; ip[o]=a4;
}

// user round 2 + combine: up = spmm(ip), u2 = softmax(spmm(i1)); u_g fused
__global__ __launch_bounds__(256) void user2_kernel(
    const int* __restrict__ ptr, const int* __restrict__ idx, const float* __restrict__ val,
    const float* __restrict__ ip, const float* __restrict__ i1,
    const float* __restrict__ idemb, const float* __restrict__ u1,
    const float* __restrict__ iu, const float* __restrict__ tu, const float* __restrict__ ufi,
    float* __restrict__ up, float* __restrict__ u2b, float* __restrict__ ug, int nrows)
{
  int row = blockIdx.x*4 + (threadIdx.x >> 6);
  int lane = threadIdx.x & 63;
  if (row >= nrows) return;
  int p0 = ptr[row], p1 = ptr[row+1];
  float aup=0.f, au2=0.f;
  for (int p = p0; p < p1; ++p) {
    int j = idx[p]; float v = val[p];
    size_t b = (size_t)j*64 + lane;
    aup = fmaf(v, ip[b], aup);
    au2 = fmaf(v, i1[b], au2);
  }
  // softmax(au2) over 64 lanes
  float m = au2;
#pragma unroll
  for (int o2=32;o2;o2>>=1) m = fmaxf(m, __shfl_xor(m, o2));
  float e = expf(au2 - m);
  float s = e;
#pragma unroll
  for (int o2=32;o2;o2>>=1) s += __shfl_xor(s, o2);
  float u2 = e / s;
  size_t o = (size_t)row*64 + lane;
  up[o] = aup; u2b[o] = u2;
  // combine u_g
  float e0 = idemb[o], e1 = u1[o];
  float v1 = iu[o], v2 = tu[o], v3 = aup, v4 = ufi[o];
  float n1=v1*v1, n2=v2*v2, n3=v3*v3, n4=v4*v4;
#pragma unroll
  for (int o2=32;o2;o2>>=1) {
    n1 += __shfl_xor(n1, o2); n2 += __shfl_xor(n2, o2);
    n3 += __shfl_xor(n3, o2); n4 += __shfl_xor(n4, o2);
  }
  n1 = fmaxf(sqrtf(n1), 1e-12f); n2 = fmaxf(sqrtf(n2), 1e-12f);
  n3 = fmaxf(sqrtf(n3), 1e-12f); n4 = fmaxf(sqrtf(n4), 1e-12f);
  ug[o] = (e0+e1+u2)*(1.f/3.f)
        + 0.02f*(v1/n1) + 0.02f*(v2/n2)
        + 0.30f*(v3/n3) + 0.30f*(v4/n4);
}

// item round 2 + combine: i2 = softmax(spmm(u2)); i_g fused
__global__ __launch_bounds__(256) void item2_kernel(
    const int* __restrict__ ptr, const int* __restrict__ idx, const float* __restrict__ val,
    const float* __restrict__ u2b,
    const float* __restrict__ idemb, const float* __restrict__ i1,
    const float* __restrict__ ii, const float* __restrict__ ti,
    const float* __restrict__ ip, const float* __restrict__ ifo,
    float* __restrict__ ig, int nrows)
{
  int row = blockIdx.x*4 + (threadIdx.x >> 6);
  int lane = threadIdx.x & 63;
  if (row >= nrows) return;
  int p0 = ptr[row], p1 = ptr[row+1];
  float ai2=0.f;
  for (int p = p0; p < p1; ++p) {
    int j = idx[p]; float v = val[p];
    ai2 = fmaf(v, u2b[(size_t)j*64 + lane], ai2);
  }
  float m = ai2;
#pragma unroll
  for (int o2=32;o2;o2>>=1) m = fmaxf(m, __shfl_xor(m, o2));
  float e = expf(ai2 - m);
  float s = e;
#pragma unroll
  for (int o2=32;o2;o2>>=1) s += __shfl_xor(s, o2);
  float i2 = e / s;
  size_t o = (size_t)row*64 + lane;
  float e0 = idemb[o], e1 = i1[o];
  float v1 = ii[o], v2 = ti[o], v3 = ip[o], v4 = ifo[o];
  float n1=v1*v1, n2=v2*v2, n3=v3*v3, n4=v4*v4;
#pragma unroll
  for (int o2=32;o2;o2>>=1) {
    n1 += __shfl_xor(n1, o2); n2 += __shfl_xor(n2, o2);
    n3 += __shfl_xor(n3, o2); n4 += __shfl_xor(n4, o2);
  }
  n1 = fmaxf(sqrtf(n1), 1e-12f); n2 = fmaxf(sqrtf(n2), 1e-12f);
  n3 = fmaxf(sqrtf(n3), 1e-12f); n4 = fmaxf(sqrtf(n4), 1e-12f);
  ig[o] = (e0+e1+i2)*(1.f/3.f)
        + 0.02f*(v1/n1) + 0.02f*(v2/n2)
        + 0.30f*(v3/n3) + 0.30f*(v4/n4);
}

// ===================== host =====================
extern "C" void kernel_launch(void* const* d_in, const int* in_sizes, int n_in,
                              void* d_out, int out_size, void* d_ws, size_t ws_size,
                              hipStream_t stream)
{
  const int*   ui_rows     = (const int*)d_in[0];
  const int*   ui_cols     = (const int*)d_in[1];
  const float* ui_vals     = (const float*)d_in[2];
  const float* image_feats = (const float*)d_in[3];
  const float* text_feats  = (const float*)d_in[4];
  const float* user_feats0 = (const float*)d_in[5];
  const float* item_title  = (const float*)d_in[6];
  const float* W_img = (const float*)d_in[7];
  const float* b_img = (const float*)d_in[8];
  const float* W_txt = (const float*)d_in[9];
  const float* b_txt = (const float*)d_in[10];
  const float* W_usr = (const float*)d_in[11];
  const float* b_usr = (const float*)d_in[12];
  const float* W_itm = (const float*)d_in[13];
  const float* b_itm = (const float*)d_in[14];
  const float* user_id_emb = (const float*)d_in[15];
  const float* item_id_emb = (const float*)d_in[16];
  const int nnz = in_sizes[0];

  float* out = (float*)d_out;
  const size_t OU = (size_t)NU*64, OI = (size_t)NI*64;
  size_t off = 0;
  float* o_ug   = out + off; off += OU;   // u_g
  float* o_ig   = out + off; off += OI;   // i_g
  float* o_ii   = out + off; off += OI;   // image_item
  float* o_ti   = out + off; off += OI;   // text_item
  float* o_iu   = out + off; off += OU;   // image_user
  float* o_tu   = out + off; off += OU;   // text_user
  float* o_ue   = out + off; off += OU;   // usr_e
  float* o_ifo  = out + off; off += OI;   // item_feats_out
  float* o_up   = out + off; off += OU;   // user_prof
  float* o_ip   = out + off; off += OI;   // item_prof
  float* o_ufi  = out + off; off += OU;   // user_feat_from_item
  float* o_mask = out + off; off += NMASK;// mask_nodes (as float)
  float* o_ri   = out + off; off += OI;   // raw_image
  float* o_rt   = out + off; off += OI;   // raw_text
  float* o_rit  = out + off; off += OI;   // raw_item

  // workspace layout (accumulator zone first, memset each call)
  char* wp = (char*)d_ws;
  auto walloc = [&](size_t bytes) -> char* {
    char* r = wp; wp += (bytes + 255) & ~(size_t)255; return r;
  };
  int*   cnt_u = (int*)  walloc((size_t)NU*4);
  int*   cnt_i = (int*)  walloc((size_t)NI*4);
  int*   flag  = (int*)  walloc((size_t)NI*4);
  float* means = (float*)walloc(3*64*4);
  int*   rankA = (int*)  walloc((size_t)NI*4);
  int*   rankB = (int*)  walloc((size_t)NI*4);
  size_t zero_bytes = (size_t)(wp - (char*)d_ws);
  uint32_t* sk    = (uint32_t*)walloc(4*4);
  uint32_t* bits  = (uint32_t*)walloc((size_t)NI*4);
  uint32_t* permA = (uint32_t*)walloc((size_t)NI*4);
  uint32_t* permB = (uint32_t*)walloc((size_t)NI*4);
  int*   ptr_u = (int*)  walloc((size_t)(NU+1)*4);
  int*   ptr_i = (int*)  walloc((size_t)(NI+1)*4);
  int*   cur_u = (int*)  walloc((size_t)NU*4);
  int*   cur_i = (int*)  walloc((size_t)NI*4);
  int*   idx_u = (int*)  walloc((size_t)nnz*4);
  float* val_u = (float*)walloc((size_t)nnz*4);
  int*   idx_i = (int*)  walloc((size_t)nnz*4);
  float* val_i = (float*)walloc((size_t)nnz*4);
  float* u1    = (float*)walloc(OU*4);
  float* i1    = (float*)walloc(OI*4);
  float* u2b   = (float*)walloc(OU*4);
  int*   part  = (int*)  walloc((size_t)NU*4);
  int*   bsum  = (int*)  walloc(256*4);
  int*   bptr  = (int*)  walloc(257*4);
  float* pbuf  = (float*)walloc((size_t)4*NI*64*4);  // K-split partials (max 4 chunks x NI)
  float* mean_img = means, *mean_txt = means + 64, *mean_itm = means + 128;

  hipMemsetAsync(d_ws, 0, zero_bytes, stream);

  // --- mask_nodes: exact JAX permutation(key(42), 20000)[:2000], partitionable path ---
  seed_kernel<<<1, 64, 0, stream>>>(sk);
  dim3 rgrid(cdiv(NI,256), NI/RCH);
  bits_kernel<<<cdiv(NI,256), 256, 0, stream>>>(sk, 0, bits, NI);
  rank_partial_kernel<<<rgrid, 256, 0, stream>>>(bits, rankA, NI);
  scatter_rank_kernel<<<cdiv(NI,256), 256, 0, stream>>>(rankA, nullptr, permA, NI, 1);
  bits_kernel<<<cdiv(NI,256), 256, 0, stream>>>(sk, 1, bits, NI);
  rank_partial_kernel<<<rgrid, 256, 0, stream>>>(bits, rankB, NI);
  scatter_rank_kernel<<<cdiv(NI,256), 256, 0, stream>>>(rankB, permA, permB, NI, 0);
  mask_kernel<<<cdiv(NMASK,256), 256, 0, stream>>>(permB, o_mask, flag);

  // --- raw projections (bf16 MFMA, K-split) ---
  auto gemm = [&](const float* X, const float* W, const float* b, float* o, int N, int K, int nch){
    dim3 g(cdiv(N,64), nch);
    gemm_mfma_kernel<<<g, 256, 0, stream>>>(X, W, pbuf, N, K, K/nch);
    gemm_reduce_kernel<<<cdiv(N*64,256), 256, 0, stream>>>(pbuf, b, o, N, nch);
  };
  gemm(image_feats, W_img, b_img, o_ri,  NI, 4096, 4);
  gemm(text_feats,  W_txt, b_txt, o_rt,  NI, 768,  2);
  gemm(item_title,  W_itm, b_itm, o_rit, NI, 1536, 2);
  gemm(user_feats0, W_usr, b_usr, o_ue,  NU, 1536, 2);

  // masked-row projection == column-mean of raw projection (projection is linear)
  colmean_kernel<<<128, 256, 0, stream>>>(o_ri,  mean_img, NI, 1.f/NI);
  colmean_kernel<<<128, 256, 0, stream>>>(o_rt,  mean_txt, NI, 1.f/NI);
  colmean_kernel<<<128, 256, 0, stream>>>(o_rit, mean_itm, NI, 1.f/NI);

  // --- CSR build (rows->users, cols->items) ---
  hist_kernel<<<cdiv(nnz,256), 256, 0, stream>>>(ui_rows, ui_cols, cnt_u, cnt_i, nnz);
  {
    int nbu = cdiv(NU,256);
    scan_block_kernel<<<nbu, 256, 0, stream>>>(cnt_u, part, bsum, NU);
    exscan_kernel<<<1, 64, 0, stream>>>(bsum, bptr, nbu);
    scan_add_kernel<<<nbu, 256, 0, stream>>>(part, bptr, ptr_u, NU, nbu);
    int nbi = cdiv(NI,256);
    scan_block_kernel<<<nbi, 256, 0, stream>>>(cnt_i, part, bsum, NI);
    exscan_kernel<<<1, 64, 0, stream>>>(bsum, bptr, nbi);
    scan_add_kernel<<<nbi, 256, 0, stream>>>(part, bptr, ptr_i, NI, nbi);
  }
  hipMemcpyAsync(cur_u, ptr_u, (size_t)NU*4, hipMemcpyDeviceToDevice, stream);
  hipMemcpyAsync(cur_i, ptr_i, (size_t)NI*4, hipMemcpyDeviceToDevice, stream);
  scatter_kernel<<<cdiv(nnz,256), 256, 0, stream>>>(ui_rows, ui_cols, ui_vals,
      cur_u, cur_i, idx_u, val_u, idx_i, val_i, nnz);

  const int GU = cdiv(NU,4), GI = cdiv(NI,4);
  // fused SpMM rounds
  spmm_user1_kernel<<<GU,256,0,stream>>>(ptr_u, idx_u, val_u,
      o_ri, o_rt, o_rit, item_id_emb, flag, means,
      o_iu, o_tu, o_ufi, u1, NU);
  spmm_item1_kernel<<<GI,256,0,stream>>>(ptr_i, idx_i, val_i,
      o_iu, o_tu, o_ufi, u1, o_ue,
      o_ii, o_ti, o_ifo, i1, o_ip, NI);
  user2_kernel<<<GU,256,0,stream>>>(ptr_u, idx_u, val_u,
      o_ip, i1, user_id_emb, u1, o_iu, o_tu, o_ufi,
      o_up, u2b, o_ug, NU);
  item2_kernel<<<GI,256,0,stream>>>(ptr_i, idx_i, val_i,
      u2b, item_id_emb, i1, o_ii, o_ti, o_ip, o_ifo,
      o_ig, NI);
}

// Round 7
// 882.518 us; speedup vs baseline: 3.3169x; 1.0627x over previous
//
#include <hip/hip_runtime.h>
#include <cstdint>
#include <cstddef>

#define NU 30000
#define NI 20000
#define NMASK 2000

static inline int cdiv(int a, int b){ return (a + b - 1) / b; }

typedef __attribute__((ext_vector_type(8))) short bf16x8;
typedef __attribute__((ext_vector_type(4))) float f32x4;

// ===================== threefry-2x32 (exact JAX semantics) =====================
__device__ __forceinline__ uint32_t rotl32(uint32_t x, int r){ return (x<<r)|(x>>(32-r)); }

__device__ __forceinline__ void tf2x32(uint32_t k0, uint32_t k1,
                                       uint32_t x0, uint32_t x1,
                                       uint32_t& o0, uint32_t& o1)
{
  uint32_t k2 = k0 ^ k1 ^ 0x1BD11BDAu;
  x0 += k0; x1 += k1;
#define TFR(r) { x0 += x1; x1 = rotl32(x1,(r)); x1 ^= x0; }
  TFR(13) TFR(15) TFR(26) TFR(6)
  x0 += k1; x1 += k2 + 1u;
  TFR(17) TFR(29) TFR(16) TFR(24)
  x0 += k2; x1 += k0 + 2u;
  TFR(13) TFR(15) TFR(26) TFR(6)
  x0 += k0; x1 += k1 + 3u;
  TFR(17) TFR(29) TFR(16) TFR(24)
  x0 += k1; x1 += k2 + 4u;
  TFR(13) TFR(15) TFR(26) TFR(6)
  x0 += k2; x1 += k0 + 5u;
#undef TFR
  o0 = x0; o1 = x1;
}

__global__ void seed_kernel(uint32_t* __restrict__ sk)
{
  if (threadIdx.x == 0 && blockIdx.x == 0) {
    uint32_t c0,c1, s0,s1, t0,t1;
    tf2x32(0u,42u, 0u,0u, c0,c1);
    tf2x32(0u,42u, 0u,1u, s0,s1);
    tf2x32(c0,c1, 0u,1u, t0,t1);
    sk[0]=s0; sk[1]=s1;
    sk[2]=t0; sk[3]=t1;
  }
}

__global__ __launch_bounds__(256) void bits_kernel(const uint32_t* __restrict__ sk, int which,
                                                   uint32_t* __restrict__ bits, int n)
{
  int i = blockIdx.x*256 + threadIdx.x;
  if (i < n) {
    uint32_t o0,o1;
    tf2x32(sk[2*which], sk[2*which+1], 0u, (uint32_t)i, o0,o1);
    bits[i] = o0 ^ o1;
  }
}

// ===================== stable rank sort, j-split =====================
#define RCH 2000
__global__ __launch_bounds__(256) void rank_partial_kernel(
    const uint32_t* __restrict__ keys, int* __restrict__ rank, int n)
{
  __shared__ uint32_t lk[RCH];
  int i = blockIdx.x*256 + threadIdx.x;
  int c0 = blockIdx.y * RCH;
  int csz = min(RCH, n - c0);
  for (int j = threadIdx.x; j < csz; j += 256) lk[j] = keys[c0 + j];
  __syncthreads();
  if (i >= n) return;
  uint32_t k = keys[i];
  int r = 0;
  const uint4* lk4 = reinterpret_cast<const uint4*>(lk);
  for (int j = 0; j < csz; j += 16) {
    uint4 a = lk4[(j>>2)+0];
    uint4 b = lk4[(j>>2)+1];
    uint4 c = lk4[(j>>2)+2];
    uint4 d = lk4[(j>>2)+3];
    int g = c0 + j;
    r += (int)(a.x < k) | (int)((a.x == k) & (g + 0  < i));
    r += (int)(a.y < k) | (int)((a.y == k) & (g + 1  < i));
    r += (int)(a.z < k) | (int)((a.z == k) & (g + 2  < i));
    r += (int)(a.w < k) | (int)((a.w == k) & (g + 3  < i));
    r += (int)(b.x < k) | (int)((b.x == k) & (g + 4  < i));
    r += (int)(b.y < k) | (int)((b.y == k) & (g + 5  < i));
    r += (int)(b.z < k) | (int)((b.z == k) & (g + 6  < i));
    r += (int)(b.w < k) | (int)((b.w == k) & (g + 7  < i));
    r += (int)(c.x < k) | (int)((c.x == k) & (g + 8  < i));
    r += (int)(c.y < k) | (int)((c.y == k) & (g + 9  < i));
    r += (int)(c.z < k) | (int)((c.z == k) & (g + 10 < i));
    r += (int)(c.w < k) | (int)((c.w == k) & (g + 11 < i));
    r += (int)(d.x < k) | (int)((d.x == k) & (g + 12 < i));
    r += (int)(d.y < k) | (int)((d.y == k) & (g + 13 < i));
    r += (int)(d.z < k) | (int)((d.z == k) & (g + 14 < i));
    r += (int)(d.w < k) | (int)((d.w == k) & (g + 15 < i));
  }
  atomicAdd(&rank[i], r);
}

__global__ __launch_bounds__(256) void scatter_rank_kernel(
    const int* __restrict__ rank, const uint32_t* __restrict__ vin,
    uint32_t* __restrict__ vout, int n, int ident)
{
  int i = blockIdx.x*256 + threadIdx.x;
  if (i < n) vout[rank[i]] = ident ? (uint32_t)i : vin[i];
}

__global__ __launch_bounds__(256) void mask_kernel(const uint32_t* __restrict__ perm,
                                                   float* __restrict__ mask_out,
                                                   int* __restrict__ flag)
{
  int i = blockIdx.x*256 + threadIdx.x;
  if (i < NMASK) {
    uint32_t v = perm[i];
    mask_out[i] = (float)v;
    flag[v] = 1;
  }
}

// ===================== bf16 helpers =====================
__device__ __forceinline__ ushort f2bf(float f){
  union { float f; uint32_t u; } c; c.f = f;
  uint32_t u = c.u;
  return (ushort)((u + 0x7fffu + ((u >> 16) & 1u)) >> 16);
}
__device__ __forceinline__ uint32_t pk2(float a, float b){
  return (uint32_t)f2bf(a) | ((uint32_t)f2bf(b) << 16);
}
__device__ __forceinline__ float lobf(uint32_t p){
  union { uint32_t u; float f; } c; c.u = p << 16; return c.f;
}
__device__ __forceinline__ float hibf(uint32_t p){
  union { uint32_t u; float f; } c; c.u = p & 0xffff0000u; return c.f;
}
__device__ __forceinline__ float bf2f(ushort h){
  union { uint32_t u; float f; } c; c.u = (uint32_t)h << 16; return c.f;
}

// ===================== MFMA GEMM: out(N,64) = X(N,K) @ W(64,K)^T =====================
__global__ __launch_bounds__(256) void gemm_mfma_kernel(
    const float* __restrict__ X, const float* __restrict__ W,
    float* __restrict__ pbuf, int N, int K, int klen)
{
  __shared__ ushort Xs[64][72];
  __shared__ ushort Ws[64][72];
  const int tid = threadIdx.x;
  const int row0 = blockIdx.x * 64;
  const int kbeg = blockIdx.y * klen;
  const int lane = tid & 63;
  const int wr = tid >> 6;
  const int lrow = lane & 15;
  const int kslot = lane >> 4;
  f32x4 acc[4] = {f32x4{0,0,0,0},f32x4{0,0,0,0},f32x4{0,0,0,0},f32x4{0,0,0,0}};

  const int sr = tid >> 4;
  const int sc = (tid & 15) * 4;

  for (int k0 = kbeg; k0 < kbeg + klen; k0 += 64) {
#pragma unroll
    for (int i = 0; i < 4; ++i) {
      int r = sr + 16*i;
      int gr = row0 + r;
      float4 v = make_float4(0.f,0.f,0.f,0.f);
      if (gr < N) v = *reinterpret_cast<const float4*>(X + (size_t)gr*K + k0 + sc);
      ushort4 h; h.x=f2bf(v.x); h.y=f2bf(v.y); h.z=f2bf(v.z); h.w=f2bf(v.w);
      *reinterpret_cast<ushort4*>(&Xs[r][sc]) = h;
      float4 w = *reinterpret_cast<const float4*>(W + (size_t)r*K + k0 + sc);
      ushort4 hw; hw.x=f2bf(w.x); hw.y=f2bf(w.y); hw.z=f2bf(w.z); hw.w=f2bf(w.w);
      *reinterpret_cast<ushort4*>(&Ws[r][sc]) = hw;
    }
    __syncthreads();
#pragma unroll
    for (int ks = 0; ks < 2; ++ks) {
      int kb = ks*32 + kslot*8;
      bf16x8 af = *reinterpret_cast<const bf16x8*>(&Xs[wr*16 + lrow][kb]);
#pragma unroll
      for (int ct = 0; ct < 4; ++ct) {
        bf16x8 bfr = *reinterpret_cast<const bf16x8*>(&Ws[ct*16 + lrow][kb]);
        acc[ct] = __builtin_amdgcn_mfma_f32_16x16x32_bf16(af, bfr, acc[ct], 0, 0, 0);
      }
    }
    __syncthreads();
  }
  float* pb = pbuf + (size_t)blockIdx.y * N * 64;
#pragma unroll
  for (int ct = 0; ct < 4; ++ct)
#pragma unroll
    for (int j = 0; j < 4; ++j) {
      int gr = row0 + wr*16 + kslot*4 + j;
      if (gr < N) pb[(size_t)gr*64 + ct*16 + lrow] = acc[ct][j];
    }
}

// out[r][c] = bias[c] + sum_ch pbuf[ch][r][c]; optional bf16 copy
__global__ __launch_bounds__(256) void gemm_reduce_kernel(
    const float* __restrict__ pbuf, const float* __restrict__ bias,
    float* __restrict__ out, ushort* __restrict__ obf, int N, int nch)
{
  int i = blockIdx.x*256 + threadIdx.x;
  if (i >= N*64) return;
  float s = bias[i & 63];
  for (int ch = 0; ch < nch; ++ch) s += pbuf[(size_t)ch*N*64 + i];
  out[i] = s;
  if (obf) obf[i] = f2bf(s);
}

// pack pair to bf16x2 + optional fused column means
__global__ __launch_bounds__(256) void pack2_kernel(
    const float* __restrict__ a, const float* __restrict__ b,
    uint32_t* __restrict__ po, float* __restrict__ ma, float* __restrict__ mb,
    int n, float inv_n)
{
  __shared__ float red[2][256];
  int lane = threadIdx.x & 63;
  int w = threadIdx.x >> 6;
  float sa = 0.f, sb = 0.f;
  for (int r = blockIdx.x*4 + w; r < n; r += gridDim.x*4) {
    size_t i = (size_t)r*64 + lane;
    float av = a[i], bv = b[i];
    po[i] = pk2(av, bv);
    sa += av; sb += bv;
  }
  red[0][threadIdx.x] = sa; red[1][threadIdx.x] = sb;
  __syncthreads();
  if (threadIdx.x < 64) {
    if (ma) {
      float t = red[0][lane]+red[0][64+lane]+red[0][128+lane]+red[0][192+lane];
      atomicAdd(&ma[lane], t * inv_n);
    }
    if (mb) {
      float t = red[1][lane]+red[1][64+lane]+red[1][128+lane]+red[1][192+lane];
      atomicAdd(&mb[lane], t * inv_n);
    }
  }
}

// ===================== CSR build =====================
__global__ __launch_bounds__(256) void hist_kernel(const int* __restrict__ rows,
                                                   const int* __restrict__ cols,
                                                   int* __restrict__ cu, int* __restrict__ ci, int nnz)
{
  int k = blockIdx.x*256 + threadIdx.x;
  if (k < nnz) { atomicAdd(&cu[rows[k]], 1); atomicAdd(&ci[cols[k]], 1); }
}

__global__ __launch_bounds__(256) void scan_block_kernel(
    const int* __restrict__ cnt, int* __restrict__ part, int* __restrict__ bsum, int n)
{
  __shared__ int wsum[4];
  int i = blockIdx.x*256 + threadIdx.x;
  int lane = threadIdx.x & 63;
  int w = threadIdx.x >> 6;
  int v = (i < n) ? cnt[i] : 0;
  int s = v;
#pragma unroll
  for (int off = 1; off < 64; off <<= 1) {
    int t = __shfl_up(s, off);
    if (lane >= off) s += t;
  }
  if (lane == 63) wsum[w] = s;
  __syncthreads();
  int wo = 0;
#pragma unroll
  for (int k = 0; k < 4; ++k) if (k < w) wo += wsum[k];
  if (i < n) part[i] = wo + s - v;
  if (threadIdx.x == 255) bsum[blockIdx.x] = wo + s;
}

__global__ __launch_bounds__(64) void exscan_kernel(const int* __restrict__ cnt,
                                                    int* __restrict__ ptr, int n)
{
  int lane = threadIdx.x;
  int carry = 0;
  for (int base = 0; base < n; base += 64) {
    int i = base + lane;
    int v = (i < n) ? cnt[i] : 0;
    int s = v;
#pragma unroll
    for (int off = 1; off < 64; off <<= 1) {
      int t = __shfl_up(s, off);
      if (lane >= off) s += t;
    }
    if (i < n) ptr[i] = carry + s - v;
    carry += __shfl(s, 63);
  }
  if (lane == 0) ptr[n] = carry;
}

__global__ __launch_bounds__(256) void scan_add_kernel(
    const int* __restrict__ part, const int* __restrict__ bptr,
    int* __restrict__ ptr, int n, int nb)
{
  int i = blockIdx.x*256 + threadIdx.x;
  if (i < n) ptr[i] = part[i] + bptr[blockIdx.x];
  if (i == 0) ptr[n] = bptr[nb];
}

__global__ __launch_bounds__(256) void scatter_kernel(
    const int* __restrict__ rows, const int* __restrict__ cols, const float* __restrict__ vals,
    int* __restrict__ cur_u, int* __restrict__ cur_i,
    int* __restrict__ idx_u, float* __restrict__ val_u,
    int* __restrict__ idx_i, float* __restrict__ val_i, int nnz)
{
  int k = blockIdx.x*256 + threadIdx.x;
  if (k < nnz) {
    int r = rows[k], c = cols[k];
    float v = vals[k];
    int pu = atomicAdd(&cur_u[r], 1);
    idx_u[pu] = c; val_u[pu] = v;
    int pi = atomicAdd(&cur_i[c], 1);
    idx_i[pi] = r; val_i[pi] = v;
  }
}

// ===================== fused SpMMs (bf16-packed gathers) =====================
// user round 1: gathers pk(ri,rt) + pk(rit,idemb); outputs f32 + packed bf16
__global__ __launch_bounds__(256) void spmm_user1_kernel(
    const int* __restrict__ ptr, const int* __restrict__ idx, const float* __restrict__ val,
    const uint32_t* __restrict__ pk01, const uint32_t* __restrict__ pk23,
    const int* __restrict__ flag, const float* __restrict__ means,
    float* __restrict__ iu, float* __restrict__ tu, float* __restrict__ ufi, float* __restrict__ u1,
    uint32_t* __restrict__ q01, uint32_t* __restrict__ q23, int nrows)
{
  int row = blockIdx.x*4 + (threadIdx.x >> 6);
  int lane = threadIdx.x & 63;
  if (row >= nrows) return;
  int p0 = ptr[row], p1 = ptr[row+1];
  float m0 = means[lane], m1 = means[64+lane], m2 = means[128+lane];
  float a0=0.f, a1=0.f, a2=0.f, a3=0.f;
  for (int p = p0; p < p1; ++p) {
    int j = idx[p]; float v = val[p];
    size_t b = (size_t)j*64 + lane;
    uint32_t g01 = pk01[b], g23 = pk23[b];
    float x0, x1, x2, x3 = hibf(g23);
    if (flag[j]) { x0 = m0; x1 = m1; x2 = m2; }
    else { x0 = lobf(g01); x1 = hibf(g01); x2 = lobf(g23); }
    a0 = fmaf(v, x0, a0); a1 = fmaf(v, x1, a1);
    a2 = fmaf(v, x2, a2); a3 = fmaf(v, x3, a3);
  }
  size_t o = (size_t)row*64 + lane;
  iu[o]=a0; tu[o]=a1; ufi[o]=a2; u1[o]=a3;
  q01[o] = pk2(a0, a1);   // (iu,tu)
  q23[o] = pk2(a2, a3);   // (ufi,u1)
}

// item round 1: gathers pk(iu,tu) + pk(ufi,u1) + bf16 ue
__global__ __launch_bounds__(256) void spmm_item1_kernel(
    const int* __restrict__ ptr, const int* __restrict__ idx, const float* __restrict__ val,
    const uint32_t* __restrict__ q01, const uint32_t* __restrict__ q23,
    const ushort* __restrict__ ueh,
    float* __restrict__ ii, float* __restrict__ ti, float* __restrict__ ifo,
    float* __restrict__ i1, float* __restrict__ ip,
    uint32_t* __restrict__ qip1, int nrows)
{
  int row = blockIdx.x*4 + (threadIdx.x >> 6);
  int lane = threadIdx.x & 63;
  if (row >= nrows) return;
  int p0 = ptr[row], p1 = ptr[row+1];
  float a0=0.f, a1=0.f, a2=0.f, a3=0.f, a4=0.f;
  for (int p = p0; p < p1; ++p) {
    int j = idx[p]; float v = val[p];
    size_t b = (size_t)j*64 + lane;
    uint32_t g01 = q01[b], g23 = q23[b];
    float x4 = bf2f(ueh[b]);
    a0 = fmaf(v, lobf(g01), a0); a1 = fmaf(v, hibf(g01), a1);
    a2 = fmaf(v, lobf(g23), a2); a3 = fmaf(v, hibf(g23), a3);
    a4 = fmaf(v, x4, a4);
  }
  size_t o = (size_t)row*64 + lane;
  ii[o]=a0; ti[o]=a1; ifo[o]=a2; i1[o]=a3; ip[o]=a4;
  qip1[o] = pk2(a4, a3);  // (ip,i1)
}

// user round 2 + combine
__global__ __launch_bounds__(256) void user2_kernel(
    const int* __restrict__ ptr, const int* __restrict__ idx, const float* __restrict__ val,
    const uint32_t* __restrict__ qip1,
    const float* __restrict__ idemb, const float* __restrict__ u1,
    const float* __restrict__ iu, const float* __restrict__ tu, const float* __restrict__ ufi,
    float* __restrict__ up, ushort* __restrict__ u2h, float* __restrict__ ug, int nrows)
{
  int row = blockIdx.x*4 + (threadIdx.x >> 6);
  int lane = threadIdx.x & 63;
  if (row >= nrows) return;
  int p0 = ptr[row], p1 = ptr[row+1];
  float aup=0.f, au2=0.f;
  for (int p = p0; p < p1; ++p) {
    int j = idx[p]; float v = val[p];
    uint32_t g = qip1[(size_t)j*64 + lane];
    aup = fmaf(v, lobf(g), aup);
    au2 = fmaf(v, hibf(g), au2);
  }
  float m = au2;
#pragma unroll
  for (int o2=32;o2;o2>>=1) m = fmaxf(m, __shfl_xor(m, o2));
  float e = expf(au2 - m);
  float s = e;
#pragma unroll
  for (int o2=32;o2;o2>>=1) s += __shfl_xor(s, o2);
  float u2 = e / s;
  size_t o = (size_t)row*64 + lane;
  up[o] = aup; u2h[o] = f2bf(u2);
  float e0 = idemb[o], e1 = u1[o];
  float v1 = iu[o], v2 = tu[o], v3 = aup, v4 = ufi[o];
  float n1=v1*v1, n2=v2*v2, n3=v3*v3, n4=v4*v4;
#pragma unroll
  for (int o2=32;o2;o2>>=1) {
    n1 += __shfl_xor(n1, o2); n2 += __shfl_xor(n2, o2);
    n3 += __shfl_xor(n3, o2); n4 += __shfl_xor(n4, o2);
  }
  n1 = fmaxf(sqrtf(n1), 1e-12f); n2 = fmaxf(sqrtf(n2), 1e-12f);
  n3 = fmaxf(sqrtf(n3), 1e-12f); n4 = fmaxf(sqrtf(n4), 1e-12f);
  ug[o] = (e0+e1+u2)*(1.f/3.f)
        + 0.02f*(v1/n1) + 0.02f*(v2/n2)
        + 0.30f*(v3/n3) + 0.30f*(v4/n4);
}

// item round 2 + combine
__global__ __launch_bounds__(256) void item2_kernel(
    const int* __restrict__ ptr, const int* __restrict__ idx, const float* __restrict__ val,
    const ushort* __restrict__ u2h,
    const float* __restrict__ idemb, const float* __restrict__ i1,
    const float* __restrict__ ii, const float* __restrict__ ti,
    const float* __restrict__ ip, const float* __restrict__ ifo,
    float* __restrict__ ig, int nrows)
{
  int row = blockIdx.x*4 + (threadIdx.x >> 6);
  int lane = threadIdx.x & 63;
  if (row >= nrows) return;
  int p0 = ptr[row], p1 = ptr[row+1];
  float ai2=0.f;
  for (int p = p0; p < p1; ++p) {
    int j = idx[p]; float v = val[p];
    ai2 = fmaf(v, bf2f(u2h[(size_t)j*64 + lane]), ai2);
  }
  float m = ai2;
#pragma unroll
  for (int o2=32;o2;o2>>=1) m = fmaxf(m, __shfl_xor(m, o2));
  float e = expf(ai2 - m);
  float s = e;
#pragma unroll
  for (int o2=32;o2;o2>>=1) s += __shfl_xor(s, o2);
  float i2 = e / s;
  size_t o = (size_t)row*64 + lane;
  float e0 = idemb[o], e1 = i1[o];
  float v1 = ii[o], v2 = ti[o], v3 = ip[o], v4 = ifo[o];
  float n1=v1*v1, n2=v2*v2, n3=v3*v3, n4=v4*v4;
#pragma unroll
  for (int o2=32;o2;o2>>=1) {
    n1 += __shfl_xor(n1, o2); n2 += __shfl_xor(n2, o2);
    n3 += __shfl_xor(n3, o2); n4 += __shfl_xor(n4, o2);
  }
  n1 = fmaxf(sqrtf(n1), 1e-12f); n2 = fmaxf(sqrtf(n2), 1e-12f);
  n3 = fmaxf(sqrtf(n3), 1e-12f); n4 = fmaxf(sqrtf(n4), 1e-12f);
  ig[o] = (e0+e1+i2)*(1.f/3.f)
        + 0.02f*(v1/n1) + 0.02f*(v2/n2)
        + 0.30f*(v3/n3) + 0.30f*(v4/n4);
}

// ===================== host =====================
extern "C" void kernel_launch(void* const* d_in, const int* in_sizes, int n_in,
                              void* d_out, int out_size, void* d_ws, size_t ws_size,
                              hipStream_t stream)
{
  const int*   ui_rows     = (const int*)d_in[0];
  const int*   ui_cols     = (const int*)d_in[1];
  const float* ui_vals     = (const float*)d_in[2];
  const float* image_feats = (const float*)d_in[3];
  const float* text_feats  = (const float*)d_in[4];
  const float* user_feats0 = (const float*)d_in[5];
  const float* item_title  = (const float*)d_in[6];
  const float* W_img = (const float*)d_in[7];
  const float* b_img = (const float*)d_in[8];
  const float* W_txt = (const float*)d_in[9];
  const float* b_txt = (const float*)d_in[10];
  const float* W_usr = (const float*)d_in[11];
  const float* b_usr = (const float*)d_in[12];
  const float* W_itm = (const float*)d_in[13];
  const float* b_itm = (const float*)d_in[14];
  const float* user_id_emb = (const float*)d_in[15];
  const float* item_id_emb = (const float*)d_in[16];
  const int nnz = in_sizes[0];

  float* out = (float*)d_out;
  const size_t OU = (size_t)NU*64, OI = (size_t)NI*64;
  size_t off = 0;
  float* o_ug   = out + off; off += OU;
  float* o_ig   = out + off; off += OI;
  float* o_ii   = out + off; off += OI;
  float* o_ti   = out + off; off += OI;
  float* o_iu   = out + off; off += OU;
  float* o_tu   = out + off; off += OU;
  float* o_ue   = out + off; off += OU;
  float* o_ifo  = out + off; off += OI;
  float* o_up   = out + off; off += OU;
  float* o_ip   = out + off; off += OI;
  float* o_ufi  = out + off; off += OU;
  float* o_mask = out + off; off += NMASK;
  float* o_ri   = out + off; off += OI;
  float* o_rt   = out + off; off += OI;
  float* o_rit  = out + off; off += OI;

  char* wp = (char*)d_ws;
  auto walloc = [&](size_t bytes) -> char* {
    char* r = wp; wp += (bytes + 255) & ~(size_t)255; return r;
  };
  int*   cnt_u = (int*)  walloc((size_t)NU*4);
  int*   cnt_i = (int*)  walloc((size_t)NI*4);
  int*   flag  = (int*)  walloc((size_t)NI*4);
  float* means = (float*)walloc(3*64*4);
  int*   rankA = (int*)  walloc((size_t)NI*4);
  int*   rankB = (int*)  walloc((size_t)NI*4);
  size_t zero_bytes = (size_t)(wp - (char*)d_ws);
  uint32_t* sk    = (uint32_t*)walloc(4*4);
  uint32_t* bits  = (uint32_t*)walloc((size_t)NI*4);
  uint32_t* permA = (uint32_t*)walloc((size_t)NI*4);
  uint32_t* permB = (uint32_t*)walloc((size_t)NI*4);
  int*   ptr_u = (int*)  walloc((size_t)(NU+1)*4);
  int*   ptr_i = (int*)  walloc((size_t)(NI+1)*4);
  int*   cur_u = (int*)  walloc((size_t)NU*4);
  int*   cur_i = (int*)  walloc((size_t)NI*4);
  int*   idx_u = (int*)  walloc((size_t)nnz*4);
  float* val_u = (float*)walloc((size_t)nnz*4);
  int*   idx_i = (int*)  walloc((size_t)nnz*4);
  float* val_i = (float*)walloc((size_t)nnz*4);
  float* u1    = (float*)walloc(OU*4);
  float* i1    = (float*)walloc(OI*4);
  int*   part  = (int*)  walloc((size_t)NU*4);
  int*   bsum  = (int*)  walloc(256*4);
  int*   bptr  = (int*)  walloc(257*4);
  uint32_t* pk_rirt  = (uint32_t*)walloc(OI*4);
  uint32_t* pk_ritid = (uint32_t*)walloc(OI*4);
  uint32_t* q01      = (uint32_t*)walloc(OU*4);
  uint32_t* q23      = (uint32_t*)walloc(OU*4);
  uint32_t* qip1     = (uint32_t*)walloc(OI*4);
  ushort*   ue_bf    = (ushort*)  walloc(OU*2);
  ushort*   u2h      = (ushort*)  walloc(OU*2);
  float* pbuf  = (float*)walloc((size_t)8*NU*64*4);   // K-split partials
  float* mean_img = means, *mean_txt = means + 64, *mean_itm = means + 128;

  hipMemsetAsync(d_ws, 0, zero_bytes, stream);

  // --- mask_nodes: exact JAX permutation(key(42), 20000)[:2000] ---
  seed_kernel<<<1, 64, 0, stream>>>(sk);
  dim3 rgrid(cdiv(NI,256), NI/RCH);
  bits_kernel<<<cdiv(NI,256), 256, 0, stream>>>(sk, 0, bits, NI);
  rank_partial_kernel<<<rgrid, 256, 0, stream>>>(bits, rankA, NI);
  scatter_rank_kernel<<<cdiv(NI,256), 256, 0, stream>>>(rankA, nullptr, permA, NI, 1);
  bits_kernel<<<cdiv(NI,256), 256, 0, stream>>>(sk, 1, bits, NI);
  rank_partial_kernel<<<rgrid, 256, 0, stream>>>(bits, rankB, NI);
  scatter_rank_kernel<<<cdiv(NI,256), 256, 0, stream>>>(rankB, permA, permB, NI, 0);
  mask_kernel<<<cdiv(NMASK,256), 256, 0, stream>>>(permB, o_mask, flag);

  // --- raw projections (bf16 MFMA, K-split) ---
  auto gemm = [&](const float* X, const float* W, const float* b, float* o, ushort* obf,
                  int N, int K, int nch){
    dim3 g(cdiv(N,64), nch);
    gemm_mfma_kernel<<<g, 256, 0, stream>>>(X, W, pbuf, N, K, K/nch);
    gemm_reduce_kernel<<<cdiv(N*64,256), 256, 0, stream>>>(pbuf, b, o, obf, N, nch);
  };
  gemm(image_feats, W_img, b_img, o_ri,  nullptr, NI, 4096, 8);
  gemm(text_feats,  W_txt, b_txt, o_rt,  nullptr, NI, 768,  4);
  gemm(item_title,  W_itm, b_itm, o_rit, nullptr, NI, 1536, 4);
  gemm(user_feats0, W_usr, b_usr, o_ue,  ue_bf,   NU, 1536, 6);

  // pack gather sources + fused column means
  pack2_kernel<<<128, 256, 0, stream>>>(o_ri,  o_rt,        pk_rirt,  mean_img, mean_txt, NI, 1.f/NI);
  pack2_kernel<<<128, 256, 0, stream>>>(o_rit, item_id_emb, pk_ritid, mean_itm, nullptr,  NI, 1.f/NI);

  // --- CSR build ---
  hist_kernel<<<cdiv(nnz,256), 256, 0, stream>>>(ui_rows, ui_cols, cnt_u, cnt_i, nnz);
  {
    int nbu = cdiv(NU,256);
    scan_block_kernel<<<nbu, 256, 0, stream>>>(cnt_u, part, bsum, NU);
    exscan_kernel<<<1, 64, 0, stream>>>(bsum, bptr, nbu);
    scan_add_kernel<<<nbu, 256, 0, stream>>>(part, bptr, ptr_u, NU, nbu);
    int nbi = cdiv(NI,256);
    scan_block_kernel<<<nbi, 256, 0, stream>>>(cnt_i, part, bsum, NI);
    exscan_kernel<<<1, 64, 0, stream>>>(bsum, bptr, nbi);
    scan_add_kernel<<<nbi, 256, 0, stream>>>(part, bptr, ptr_i, NI, nbi);
  }
  hipMemcpyAsync(cur_u, ptr_u, (size_t)NU*4, hipMemcpyDeviceToDevice, stream);
  hipMemcpyAsync(cur_i, ptr_i, (size_t)NI*4, hipMemcpyDeviceToDevice, stream);
  scatter_kernel<<<cdiv(nnz,256), 256, 0, stream>>>(ui_rows, ui_cols, ui_vals,
      cur_u, cur_i, idx_u, val_u, idx_i, val_i, nnz);

  const int GU = cdiv(NU,4), GI = cdiv(NI,4);
  spmm_user1_kernel<<<GU,256,0,stream>>>(ptr_u, idx_u, val_u,
      pk_rirt, pk_ritid, flag, means,
      o_iu, o_tu, o_ufi, u1, q01, q23, NU);
  spmm_item1_kernel<<<GI,256,0,stream>>>(ptr_i, idx_i, val_i,
      q01, q23, ue_bf,
      o_ii, o_ti, o_ifo, i1, o_ip, qip1, NI);
  user2_kernel<<<GU,256,0,stream>>>(ptr_u, idx_u, val_u,
      qip1, user_id_emb, u1, o_iu, o_tu, o_ufi,
      o_up, u2h, o_ug, NU);
  item2_kernel<<<GI,256,0,stream>>>(ptr_i, idx_i, val_i,
      u2h, item_id_emb, i1, o_ii, o_ti, o_ip, o_ifo,
      o_ig, NI);
}

// Round 8
// 791.657 us; speedup vs baseline: 3.6976x; 1.1148x over previous
//
#include <hip/hip_runtime.h>
#include <hip/hip_bf16.h>
#include <cstdint>
#include <cstddef>

#define NU 30000
#define NI 20000
#define NMASK 2000
#define NBUCK 2048

static inline int cdiv(int a, int b){ return (a + b - 1) / b; }

typedef __attribute__((ext_vector_type(8))) short bf16x8;
typedef __attribute__((ext_vector_type(4))) float f32x4;

// ===================== threefry-2x32 (exact JAX semantics) =====================
__device__ __forceinline__ uint32_t rotl32(uint32_t x, int r){ return (x<<r)|(x>>(32-r)); }

__device__ __forceinline__ void tf2x32(uint32_t k0, uint32_t k1,
                                       uint32_t x0, uint32_t x1,
                                       uint32_t& o0, uint32_t& o1)
{
  uint32_t k2 = k0 ^ k1 ^ 0x1BD11BDAu;
  x0 += k0; x1 += k1;
#define TFR(r) { x0 += x1; x1 = rotl32(x1,(r)); x1 ^= x0; }
  TFR(13) TFR(15) TFR(26) TFR(6)
  x0 += k1; x1 += k2 + 1u;
  TFR(17) TFR(29) TFR(16) TFR(24)
  x0 += k2; x1 += k0 + 2u;
  TFR(13) TFR(15) TFR(26) TFR(6)
  x0 += k0; x1 += k1 + 3u;
  TFR(17) TFR(29) TFR(16) TFR(24)
  x0 += k1; x1 += k2 + 4u;
  TFR(13) TFR(15) TFR(26) TFR(6)
  x0 += k2; x1 += k0 + 5u;
#undef TFR
  o0 = x0; o1 = x1;
}

__global__ void seed_kernel(uint32_t* __restrict__ sk)
{
  if (threadIdx.x == 0 && blockIdx.x == 0) {
    uint32_t c0,c1, s0,s1, t0,t1;
    tf2x32(0u,42u, 0u,0u, c0,c1);
    tf2x32(0u,42u, 0u,1u, s0,s1);
    tf2x32(c0,c1, 0u,1u, t0,t1);
    sk[0]=s0; sk[1]=s1;
    sk[2]=t0; sk[3]=t1;
  }
}

__global__ __launch_bounds__(256) void bits_kernel(const uint32_t* __restrict__ sk, int which,
                                                   uint32_t* __restrict__ bits, int n)
{
  int i = blockIdx.x*256 + threadIdx.x;
  if (i < n) {
    uint32_t o0,o1;
    tf2x32(sk[2*which], sk[2*which+1], 0u, (uint32_t)i, o0,o1);
    bits[i] = o0 ^ o1;
  }
}

// ===================== bucketed stable sort (exact lex rank on (key,idx)) =====================
__global__ __launch_bounds__(256) void hist_bucket_kernel(
    const uint32_t* __restrict__ bits, int* __restrict__ hist, int n)
{
  int i = blockIdx.x*256 + threadIdx.x;
  if (i < n) atomicAdd(&hist[bits[i] >> 21], 1);
}

__global__ __launch_bounds__(256) void scatter_bucket_kernel(
    const uint32_t* __restrict__ bits, const int* __restrict__ bptr, int* __restrict__ cur,
    uint64_t* __restrict__ barr, int n)
{
  int i = blockIdx.x*256 + threadIdx.x;
  if (i < n) {
    uint32_t k = bits[i];
    int b = k >> 21;
    int p = bptr[b] + atomicAdd(&cur[b], 1);
    barr[p] = ((uint64_t)k << 32) | (uint32_t)i;
  }
}

// rank = bucket_base + #{same-bucket pairs < mine}; u64 (key,idx) keys are unique -> exact stable
template<int FINAL>
__global__ __launch_bounds__(256) void rank_bucket_kernel(
    const uint64_t* __restrict__ barr, const int* __restrict__ bptr,
    uint32_t* __restrict__ perm, float* __restrict__ mask_out, int* __restrict__ flag,
    int n)
{
  int p = blockIdx.x*256 + threadIdx.x;
  if (p >= n) return;
  uint64_t mk = barr[p];
  int b = (int)(mk >> 53);
  int p0 = bptr[b], p1 = bptr[b+1];
  int r = p0;
  for (int q = p0; q < p1; ++q) r += (int)(barr[q] < mk);
  uint32_t i = (uint32_t)mk;
  if (!FINAL) {
    perm[r] = i;
  } else if (r < NMASK) {
    uint32_t v = perm[i];
    mask_out[r] = (float)v;
    flag[v] = 1;
  }
}

// ===================== bf16 helpers (HW cvt, RNE) =====================
__device__ __forceinline__ ushort f2bf(float f){
  __hip_bfloat16 h = __float2bfloat16(f);
  return *reinterpret_cast<ushort*>(&h);
}
__device__ __forceinline__ uint32_t pk2(float a, float b){
  __hip_bfloat162 h = __float22bfloat162_rn(make_float2(a, b));
  return *reinterpret_cast<uint32_t*>(&h);
}
__device__ __forceinline__ uint2 f4_to_bf4(float4 v){
  __hip_bfloat162 h0 = __float22bfloat162_rn(make_float2(v.x, v.y));
  __hip_bfloat162 h1 = __float22bfloat162_rn(make_float2(v.z, v.w));
  return make_uint2(*reinterpret_cast<uint32_t*>(&h0), *reinterpret_cast<uint32_t*>(&h1));
}
__device__ __forceinline__ float lobf(uint32_t p){
  union { uint32_t u; float f; } c; c.u = p << 16; return c.f;
}
__device__ __forceinline__ float hibf(uint32_t p){
  union { uint32_t u; float f; } c; c.u = p & 0xffff0000u; return c.f;
}
__device__ __forceinline__ float bf2f(ushort h){
  union { uint32_t u; float f; } c; c.u = (uint32_t)h << 16; return c.f;
}

// ===================== MFMA GEMM: out(N,64) = X(N,K) @ W(64,K)^T =====================
__global__ __launch_bounds__(256) void gemm_mfma_kernel(
    const float* __restrict__ X, const float* __restrict__ W,
    float* __restrict__ pbuf, int N, int K, int klen)
{
  __shared__ ushort Xs[64][72];
  __shared__ ushort Ws[64][72];
  const int tid = threadIdx.x;
  const int row0 = blockIdx.x * 64;
  const int kbeg = blockIdx.y * klen;
  const int lane = tid & 63;
  const int wr = tid >> 6;
  const int lrow = lane & 15;
  const int kslot = lane >> 4;
  f32x4 acc[4] = {f32x4{0,0,0,0},f32x4{0,0,0,0},f32x4{0,0,0,0},f32x4{0,0,0,0}};

  const int sr = tid >> 4;
  const int sc = (tid & 15) * 4;

  for (int k0 = kbeg; k0 < kbeg + klen; k0 += 64) {
#pragma unroll
    for (int i = 0; i < 4; ++i) {
      int r = sr + 16*i;
      int gr = row0 + r;
      float4 v = make_float4(0.f,0.f,0.f,0.f);
      if (gr < N) v = *reinterpret_cast<const float4*>(X + (size_t)gr*K + k0 + sc);
      *reinterpret_cast<uint2*>(&Xs[r][sc]) = f4_to_bf4(v);
      float4 w = *reinterpret_cast<const float4*>(W + (size_t)r*K + k0 + sc);
      *reinterpret_cast<uint2*>(&Ws[r][sc]) = f4_to_bf4(w);
    }
    __syncthreads();
#pragma unroll
    for (int ks = 0; ks < 2; ++ks) {
      int kb = ks*32 + kslot*8;
      bf16x8 af = *reinterpret_cast<const bf16x8*>(&Xs[wr*16 + lrow][kb]);
#pragma unroll
      for (int ct = 0; ct < 4; ++ct) {
        bf16x8 bfr = *reinterpret_cast<const bf16x8*>(&Ws[ct*16 + lrow][kb]);
        acc[ct] = __builtin_amdgcn_mfma_f32_16x16x32_bf16(af, bfr, acc[ct], 0, 0, 0);
      }
    }
    __syncthreads();
  }
  float* pb = pbuf + (size_t)blockIdx.y * N * 64;
#pragma unroll
  for (int ct = 0; ct < 4; ++ct)
#pragma unroll
    for (int j = 0; j < 4; ++j) {
      int gr = row0 + wr*16 + kslot*4 + j;
      if (gr < N) pb[(size_t)gr*64 + ct*16 + lrow] = acc[ct][j];
    }
}

// out[r][c] = bias[c] + sum_ch pbuf[ch][r][c]; optional bf16 copy
__global__ __launch_bounds__(256) void gemm_reduce_kernel(
    const float* __restrict__ pbuf, const float* __restrict__ bias,
    float* __restrict__ out, ushort* __restrict__ obf, int N, int nch)
{
  int i = blockIdx.x*256 + threadIdx.x;
  if (i >= N*64) return;
  float s = bias[i & 63];
  for (int ch = 0; ch < nch; ++ch) s += pbuf[(size_t)ch*N*64 + i];
  out[i] = s;
  if (obf) obf[i] = f2bf(s);
}

// pack pair to bf16x2 + optional fused column means
__global__ __launch_bounds__(256) void pack2_kernel(
    const float* __restrict__ a, const float* __restrict__ b,
    uint32_t* __restrict__ po, float* __restrict__ ma, float* __restrict__ mb,
    int n, float inv_n)
{
  __shared__ float red[2][256];
  int lane = threadIdx.x & 63;
  int w = threadIdx.x >> 6;
  float sa = 0.f, sb = 0.f;
  for (int r = blockIdx.x*4 + w; r < n; r += gridDim.x*4) {
    size_t i = (size_t)r*64 + lane;
    float av = a[i], bv = b[i];
    po[i] = pk2(av, bv);
    sa += av; sb += bv;
  }
  red[0][threadIdx.x] = sa; red[1][threadIdx.x] = sb;
  __syncthreads();
  if (threadIdx.x < 64) {
    if (ma) {
      float t = red[0][lane]+red[0][64+lane]+red[0][128+lane]+red[0][192+lane];
      atomicAdd(&ma[lane], t * inv_n);
    }
    if (mb) {
      float t = red[1][lane]+red[1][64+lane]+red[1][128+lane]+red[1][192+lane];
      atomicAdd(&mb[lane], t * inv_n);
    }
  }
}

// ===================== CSR build =====================
__global__ __launch_bounds__(256) void hist_kernel(const int* __restrict__ rows,
                                                   const int* __restrict__ cols,
                                                   int* __restrict__ cu, int* __restrict__ ci, int nnz)
{
  int k = blockIdx.x*256 + threadIdx.x;
  if (k < nnz) { atomicAdd(&cu[rows[k]], 1); atomicAdd(&ci[cols[k]], 1); }
}

__global__ __launch_bounds__(256) void scan_block_kernel(
    const int* __restrict__ cnt, int* __restrict__ part, int* __restrict__ bsum, int n)
{
  __shared__ int wsum[4];
  int i = blockIdx.x*256 + threadIdx.x;
  int lane = threadIdx.x & 63;
  int w = threadIdx.x >> 6;
  int v = (i < n) ? cnt[i] : 0;
  int s = v;
#pragma unroll
  for (int off = 1; off < 64; off <<= 1) {
    int t = __shfl_up(s, off);
    if (lane >= off) s += t;
  }
  if (lane == 63) wsum[w] = s;
  __syncthreads();
  int wo = 0;
#pragma unroll
  for (int k = 0; k < 4; ++k) if (k < w) wo += wsum[k];
  if (i < n) part[i] = wo + s - v;
  if (threadIdx.x == 255) bsum[blockIdx.x] = wo + s;
}

__global__ __launch_bounds__(64) void exscan_kernel(const int* __restrict__ cnt,
                                                    int* __restrict__ ptr, int n)
{
  int lane = threadIdx.x;
  int carry = 0;
  for (int base = 0; base < n; base += 64) {
    int i = base + lane;
    int v = (i < n) ? cnt[i] : 0;
    int s = v;
#pragma unroll
    for (int off = 1; off < 64; off <<= 1) {
      int t = __shfl_up(s, off);
      if (lane >= off) s += t;
    }
    if (i < n) ptr[i] = carry + s - v;
    carry += __shfl(s, 63);
  }
  if (lane == 0) ptr[n] = carry;
}

__global__ __launch_bounds__(256) void scan_add_kernel(
    const int* __restrict__ part, const int* __restrict__ bptr,
    int* __restrict__ ptr, int n, int nb)
{
  int i = blockIdx.x*256 + threadIdx.x;
  if (i < n) ptr[i] = part[i] + bptr[blockIdx.x];
  if (i == 0) ptr[n] = bptr[nb];
}

__global__ __launch_bounds__(256) void scatter_kernel(
    const int* __restrict__ rows, const int* __restrict__ cols, const float* __restrict__ vals,
    int* __restrict__ cur_u, int* __restrict__ cur_i,
    int* __restrict__ idx_u, float* __restrict__ val_u,
    int* __restrict__ idx_i, float* __restrict__ val_i, int nnz)
{
  int k = blockIdx.x*256 + threadIdx.x;
  if (k < nnz) {
    int r = rows[k], c = cols[k];
    float v = vals[k];
    int pu = atomicAdd(&cur_u[r], 1);
    idx_u[pu] = c; val_u[pu] = v;
    int pi = atomicAdd(&cur_i[c], 1);
    idx_i[pi] = r; val_i[pi] = v;
  }
}

// ===================== fused SpMMs (bf16-packed gathers) =====================
__global__ __launch_bounds__(256) void spmm_user1_kernel(
    const int* __restrict__ ptr, const int* __restrict__ idx, const float* __restrict__ val,
    const uint32_t* __restrict__ pk01, const uint32_t* __restrict__ pk23,
    const int* __restrict__ flag, const float* __restrict__ means,
    float* __restrict__ iu, float* __restrict__ tu, float* __restrict__ ufi, float* __restrict__ u1,
    uint32_t* __restrict__ q01, uint32_t* __restrict__ q23, int nrows)
{
  int row = blockIdx.x*4 + (threadIdx.x >> 6);
  int lane = threadIdx.x & 63;
  if (row >= nrows) return;
  int p0 = ptr[row], p1 = ptr[row+1];
  float m0 = means[lane], m1 = means[64+lane], m2 = means[128+lane];
  float a0=0.f, a1=0.f, a2=0.f, a3=0.f;
  for (int p = p0; p < p1; ++p) {
    int j = idx[p]; float v = val[p];
    size_t b = (size_t)j*64 + lane;
    uint32_t g01 = pk01[b], g23 = pk23[b];
    float x0, x1, x2, x3 = hibf(g23);
    if (flag[j]) { x0 = m0; x1 = m1; x2 = m2; }
    else { x0 = lobf(g01); x1 = hibf(g01); x2 = lobf(g23); }
    a0 = fmaf(v, x0, a0); a1 = fmaf(v, x1, a1);
    a2 = fmaf(v, x2, a2); a3 = fmaf(v, x3, a3);
  }
  size_t o = (size_t)row*64 + lane;
  iu[o]=a0; tu[o]=a1; ufi[o]=a2; u1[o]=a3;
  q01[o] = pk2(a0, a1);
  q23[o] = pk2(a2, a3);
}

__global__ __launch_bounds__(256) void spmm_item1_kernel(
    const int* __restrict__ ptr, const int* __restrict__ idx, const float* __restrict__ val,
    const uint32_t* __restrict__ q01, const uint32_t* __restrict__ q23,
    const ushort* __restrict__ ueh,
    float* __restrict__ ii, float* __restrict__ ti, float* __restrict__ ifo,
    float* __restrict__ i1, float* __restrict__ ip,
    uint32_t* __restrict__ qip1, int nrows)
{
  int row = blockIdx.x*4 + (threadIdx.x >> 6);
  int lane = threadIdx.x & 63;
  if (row >= nrows) return;
  int p0 = ptr[row], p1 = ptr[row+1];
  float a0=0.f, a1=0.f, a2=0.f, a3=0.f, a4=0.f;
  for (int p = p0; p < p1; ++p) {
    int j = idx[p]; float v = val[p];
    size_t b = (size_t)j*64 + lane;
    uint32_t g01 = q01[b], g23 = q23[b];
    float x4 = bf2f(ueh[b]);
    a0 = fmaf(v, lobf(g01), a0); a1 = fmaf(v, hibf(g01), a1);
    a2 = fmaf(v, lobf(g23), a2); a3 = fmaf(v, hibf(g23), a3);
    a4 = fmaf(v, x4, a4);
  }
  size_t o = (size_t)row*64 + lane;
  ii[o]=a0; ti[o]=a1; ifo[o]=a2; i1[o]=a3; ip[o]=a4;
  qip1[o] = pk2(a4, a3);
}

__global__ __launch_bounds__(256) void user2_kernel(
    const int* __restrict__ ptr, const int* __restrict__ idx, const float* __restrict__ val,
    const uint32_t* __restrict__ qip1,
    const float* __restrict__ idemb, const float* __restrict__ u1,
    const float* __restrict__ iu, const float* __restrict__ tu, const float* __restrict__ ufi,
    float* __restrict__ up, ushort* __restrict__ u2h, float* __restrict__ ug, int nrows)
{
  int row = blockIdx.x*4 + (threadIdx.x >> 6);
  int lane = threadIdx.x & 63;
  if (row >= nrows) return;
  int p0 = ptr[row], p1 = ptr[row+1];
  float aup=0.f, au2=0.f;
  for (int p = p0; p < p1; ++p) {
    int j = idx[p]; float v = val[p];
    uint32_t g = qip1[(size_t)j*64 + lane];
    aup = fmaf(v, lobf(g), aup);
    au2 = fmaf(v, hibf(g), au2);
  }
  float m = au2;
#pragma unroll
  for (int o2=32;o2;o2>>=1) m = fmaxf(m, __shfl_xor(m, o2));
  float e = expf(au2 - m);
  float s = e;
#pragma unroll
  for (int o2=32;o2;o2>>=1) s += __shfl_xor(s, o2);
  float u2 = e / s;
  size_t o = (size_t)row*64 + lane;
  up[o] = aup; u2h[o] = f2bf(u2);
  float e0 = idemb[o], e1 = u1[o];
  float v1 = iu[o], v2 = tu[o], v3 = aup, v4 = ufi[o];
  float n1=v1*v1, n2=v2*v2, n3=v3*v3, n4=v4*v4;
#pragma unroll
  for (int o2=32;o2;o2>>=1) {
    n1 += __shfl_xor(n1, o2); n2 += __shfl_xor(n2, o2);
    n3 += __shfl_xor(n3, o2); n4 += __shfl_xor(n4, o2);
  }
  n1 = fmaxf(sqrtf(n1), 1e-12f); n2 = fmaxf(sqrtf(n2), 1e-12f);
  n3 = fmaxf(sqrtf(n3), 1e-12f); n4 = fmaxf(sqrtf(n4), 1e-12f);
  ug[o] = (e0+e1+u2)*(1.f/3.f)
        + 0.02f*(v1/n1) + 0.02f*(v2/n2)
        + 0.30f*(v3/n3) + 0.30f*(v4/n4);
}

__global__ __launch_bounds__(256) void item2_kernel(
    const int* __restrict__ ptr, const int* __restrict__ idx, const float* __restrict__ val,
    const ushort* __restrict__ u2h,
    const float* __restrict__ idemb, const float* __restrict__ i1,
    const float* __restrict__ ii, const float* __restrict__ ti,
    const float* __restrict__ ip, const float* __restrict__ ifo,
    float* __restrict__ ig, int nrows)
{
  int row = blockIdx.x*4 + (threadIdx.x >> 6);
  int lane = threadIdx.x & 63;
  if (row >= nrows) return;
  int p0 = ptr[row], p1 = ptr[row+1];
  float ai2=0.f;
  for (int p = p0; p < p1; ++p) {
    int j = idx[p]; float v = val[p];
    ai2 = fmaf(v, bf2f(u2h[(size_t)j*64 + lane]), ai2);
  }
  float m = ai2;
#pragma unroll
  for (int o2=32;o2;o2>>=1) m = fmaxf(m, __shfl_xor(m, o2));
  float e = expf(ai2 - m);
  float s = e;
#pragma unroll
  for (int o2=32;o2;o2>>=1) s += __shfl_xor(s, o2);
  float i2 = e / s;
  size_t o = (size_t)row*64 + lane;
  float e0 = idemb[o], e1 = i1[o];
  float v1 = ii[o], v2 = ti[o], v3 = ip[o], v4 = ifo[o];
  float n1=v1*v1, n2=v2*v2, n3=v3*v3, n4=v4*v4;
#pragma unroll
  for (int o2=32;o2;o2>>=1) {
    n1 += __shfl_xor(n1, o2); n2 += __shfl_xor(n2, o2);
    n3 += __shfl_xor(n3, o2); n4 += __shfl_xor(n4, o2);
  }
  n1 = fmaxf(sqrtf(n1), 1e-12f); n2 = fmaxf(sqrtf(n2), 1e-12f);
  n3 = fmaxf(sqrtf(n3), 1e-12f); n4 = fmaxf(sqrtf(n4), 1e-12f);
  ig[o] = (e0+e1+i2)*(1.f/3.f)
        + 0.02f*(v1/n1) + 0.02f*(v2/n2)
        + 0.30f*(v3/n3) + 0.30f*(v4/n4);
}

// ===================== host =====================
extern "C" void kernel_launch(void* const* d_in, const int* in_sizes, int n_in,
                              void* d_out, int out_size, void* d_ws, size_t ws_size,
                              hipStream_t stream)
{
  const int*   ui_rows     = (const int*)d_in[0];
  const int*   ui_cols     = (const int*)d_in[1];
  const float* ui_vals     = (const float*)d_in[2];
  const float* image_feats = (const float*)d_in[3];
  const float* text_feats  = (const float*)d_in[4];
  const float* user_feats0 = (const float*)d_in[5];
  const float* item_title  = (const float*)d_in[6];
  const float* W_img = (const float*)d_in[7];
  const float* b_img = (const float*)d_in[8];
  const float* W_txt = (const float*)d_in[9];
  const float* b_txt = (const float*)d_in[10];
  const float* W_usr = (const float*)d_in[11];
  const float* b_usr = (const float*)d_in[12];
  const float* W_itm = (const float*)d_in[13];
  const float* b_itm = (const float*)d_in[14];
  const float* user_id_emb = (const float*)d_in[15];
  const float* item_id_emb = (const float*)d_in[16];
  const int nnz = in_sizes[0];

  float* out = (float*)d_out;
  const size_t OU = (size_t)NU*64, OI = (size_t)NI*64;
  size_t off = 0;
  float* o_ug   = out + off; off += OU;
  float* o_ig   = out + off; off += OI;
  float* o_ii   = out + off; off += OI;
  float* o_ti   = out + off; off += OI;
  float* o_iu   = out + off; off += OU;
  float* o_tu   = out + off; off += OU;
  float* o_ue   = out + off; off += OU;
  float* o_ifo  = out + off; off += OI;
  float* o_up   = out + off; off += OU;
  float* o_ip   = out + off; off += OI;
  float* o_ufi  = out + off; off += OU;
  float* o_mask = out + off; off += NMASK;
  float* o_ri   = out + off; off += OI;
  float* o_rt   = out + off; off += OI;
  float* o_rit  = out + off; off += OI;

  char* wp = (char*)d_ws;
  auto walloc = [&](size_t bytes) -> char* {
    char* r = wp; wp += (bytes + 255) & ~(size_t)255; return r;
  };
  // --- zero zone ---
  int*   cnt_u = (int*)  walloc((size_t)NU*4);
  int*   cnt_i = (int*)  walloc((size_t)NI*4);
  int*   flag  = (int*)  walloc((size_t)NI*4);
  float* means = (float*)walloc(3*64*4);
  int*   h1    = (int*)  walloc(NBUCK*4);
  int*   c1    = (int*)  walloc(NBUCK*4);
  int*   h2    = (int*)  walloc(NBUCK*4);
  int*   c2    = (int*)  walloc(NBUCK*4);
  size_t zero_bytes = (size_t)(wp - (char*)d_ws);
  // --- rest ---
  uint32_t* sk    = (uint32_t*)walloc(4*4);
  uint32_t* bits  = (uint32_t*)walloc((size_t)NI*4);
  uint32_t* permA = (uint32_t*)walloc((size_t)NI*4);
  uint64_t* barr  = (uint64_t*)walloc((size_t)NI*8);
  int*   bb    = (int*)  walloc((NBUCK+1)*4);
  int*   ptr_u = (int*)  walloc((size_t)(NU+1)*4);
  int*   ptr_i = (int*)  walloc((size_t)(NI+1)*4);
  int*   cur_u = (int*)  walloc((size_t)NU*4);
  int*   cur_i = (int*)  walloc((size_t)NI*4);
  int*   idx_u = (int*)  walloc((size_t)nnz*4);
  float* val_u = (float*)walloc((size_t)nnz*4);
  int*   idx_i = (int*)  walloc((size_t)nnz*4);
  float* val_i = (float*)walloc((size_t)nnz*4);
  float* u1    = (float*)walloc(OU*4);
  float* i1    = (float*)walloc(OI*4);
  int*   part  = (int*)  walloc((size_t)NU*4);
  int*   bsum  = (int*)  walloc(256*4);
  int*   bptr  = (int*)  walloc(257*4);
  uint32_t* pk_rirt  = (uint32_t*)walloc(OI*4);
  uint32_t* pk_ritid = (uint32_t*)walloc(OI*4);
  uint32_t* q01      = (uint32_t*)walloc(OU*4);
  uint32_t* q23      = (uint32_t*)walloc(OU*4);
  uint32_t* qip1     = (uint32_t*)walloc(OI*4);
  ushort*   ue_bf    = (ushort*)  walloc(OU*2);
  ushort*   u2h      = (ushort*)  walloc(OU*2);
  float* pbuf  = (float*)walloc((size_t)8*NU*64*4);
  float* mean_img = means, *mean_txt = means + 64, *mean_itm = means + 128;

  hipMemsetAsync(d_ws, 0, zero_bytes, stream);

  // --- mask_nodes: exact JAX permutation(key(42), 20000)[:2000], bucketed stable sorts ---
  seed_kernel<<<1, 64, 0, stream>>>(sk);
  const int GB = cdiv(NI,256);
  bits_kernel<<<GB, 256, 0, stream>>>(sk, 0, bits, NI);
  hist_bucket_kernel<<<GB, 256, 0, stream>>>(bits, h1, NI);
  exscan_kernel<<<1, 64, 0, stream>>>(h1, bb, NBUCK);
  scatter_bucket_kernel<<<GB, 256, 0, stream>>>(bits, bb, c1, barr, NI);
  rank_bucket_kernel<0><<<GB, 256, 0, stream>>>(barr, bb, permA, nullptr, nullptr, NI);
  bits_kernel<<<GB, 256, 0, stream>>>(sk, 1, bits, NI);
  hist_bucket_kernel<<<GB, 256, 0, stream>>>(bits, h2, NI);
  exscan_kernel<<<1, 64, 0, stream>>>(h2, bb, NBUCK);
  scatter_bucket_kernel<<<GB, 256, 0, stream>>>(bits, bb, c2, barr, NI);
  rank_bucket_kernel<1><<<GB, 256, 0, stream>>>(barr, bb, permA, o_mask, flag, NI);

  // --- raw projections (bf16 MFMA, K-split) ---
  auto gemm = [&](const float* X, const float* W, const float* b, float* o, ushort* obf,
                  int N, int K, int nch){
    dim3 g(cdiv(N,64), nch);
    gemm_mfma_kernel<<<g, 256, 0, stream>>>(X, W, pbuf, N, K, K/nch);
    gemm_reduce_kernel<<<cdiv(N*64,256), 256, 0, stream>>>(pbuf, b, o, obf, N, nch);
  };
  gemm(image_feats, W_img, b_img, o_ri,  nullptr, NI, 4096, 8);
  gemm(text_feats,  W_txt, b_txt, o_rt,  nullptr, NI, 768,  4);
  gemm(item_title,  W_itm, b_itm, o_rit, nullptr, NI, 1536, 4);
  gemm(user_feats0, W_usr, b_usr, o_ue,  ue_bf,   NU, 1536, 6);

  // pack gather sources + fused column means
  pack2_kernel<<<128, 256, 0, stream>>>(o_ri,  o_rt,        pk_rirt,  mean_img, mean_txt, NI, 1.f/NI);
  pack2_kernel<<<128, 256, 0, stream>>>(o_rit, item_id_emb, pk_ritid, mean_itm, nullptr,  NI, 1.f/NI);

  // --- CSR build ---
  hist_kernel<<<cdiv(nnz,256), 256, 0, stream>>>(ui_rows, ui_cols, cnt_u, cnt_i, nnz);
  {
    int nbu = cdiv(NU,256);
    scan_block_kernel<<<nbu, 256, 0, stream>>>(cnt_u, part, bsum, NU);
    exscan_kernel<<<1, 64, 0, stream>>>(bsum, bptr, nbu);
    scan_add_kernel<<<nbu, 256, 0, stream>>>(part, bptr, ptr_u, NU, nbu);
    int nbi = cdiv(NI,256);
    scan_block_kernel<<<nbi, 256, 0, stream>>>(cnt_i, part, bsum, NI);
    exscan_kernel<<<1, 64, 0, stream>>>(bsum, bptr, nbi);
    scan_add_kernel<<<nbi, 256, 0, stream>>>(part, bptr, ptr_i, NI, nbi);
  }
  hipMemcpyAsync(cur_u, ptr_u, (size_t)NU*4, hipMemcpyDeviceToDevice, stream);
  hipMemcpyAsync(cur_i, ptr_i, (size_t)NI*4, hipMemcpyDeviceToDevice, stream);
  scatter_kernel<<<cdiv(nnz,256), 256, 0, stream>>>(ui_rows, ui_cols, ui_vals,
      cur_u, cur_i, idx_u, val_u, idx_i, val_i, nnz);

  const int GU = cdiv(NU,4), GI = cdiv(NI,4);
  spmm_user1_kernel<<<GU,256,0,stream>>>(ptr_u, idx_u, val_u,
      pk_rirt, pk_ritid, flag, means,
      o_iu, o_tu, o_ufi, u1, q01, q23, NU);
  spmm_item1_kernel<<<GI,256,0,stream>>>(ptr_i, idx_i, val_i,
      q01, q23, ue_bf,
      o_ii, o_ti, o_ifo, i1, o_ip, qip1, NI);
  user2_kernel<<<GU,256,0,stream>>>(ptr_u, idx_u, val_u,
      qip1, user_id_emb, u1, o_iu, o_tu, o_ufi,
      o_up, u2h, o_ug, NU);
  item2_kernel<<<GI,256,0,stream>>>(ptr_i, idx_i, val_i,
      u2h, item_id_emb, i1, o_ii, o_ti, o_ip, o_ifo,
      o_ig, NI);
}